// Round 2
// baseline (3872.736 us; speedup 1.0000x reference)
//
#include <hip/hip_runtime.h>
#include <stdint.h>

// SingleStreamBlock on MI355X. fp32 in/out (per reference), bf16 MFMA compute.
// B=2 L=2048 HID=1024 NH=16 HD=64 MLP=4096.

#define HID  1024
#define NH   16
#define HD   64
#define MLP  4096
#define D1   7168   // 3*HID + MLP
#define DQKV 3072
#define DCAT 2048
#define BB   2
#define LL   2048
#define TOK  4096

typedef __attribute__((ext_vector_type(8))) short    bf16x8;
typedef __attribute__((ext_vector_type(4))) float    f32x4;
typedef __attribute__((ext_vector_type(4))) unsigned int u32x4;

__device__ __forceinline__ float b2f(unsigned short u) {
    unsigned int v = ((unsigned int)u) << 16;
    float f; __builtin_memcpy(&f, &v, 4); return f;
}
__device__ __forceinline__ unsigned short f2b(float f) {
    unsigned int v; __builtin_memcpy(&v, &f, 4);
    unsigned int r = (v + 0x7FFFu + ((v >> 16) & 1u)) >> 16;
    return (unsigned short)r;
}

// ---------------- transpose+cast: fp32 (R x C) -> bf16 (C x R) ----------------
__global__ void k_transpose_cvt(const float* __restrict__ in,
                                unsigned short* __restrict__ out, int R, int C) {
    __shared__ float tile[32][33];
    int bx = blockIdx.x, by = blockIdx.y;
    int tx = threadIdx.x, ty = threadIdx.y;   // (32,8)
    #pragma unroll
    for (int i = 0; i < 4; i++) {
        int r = by * 32 + ty + i * 8;
        int c = bx * 32 + tx;
        tile[ty + i * 8][tx] = in[(size_t)r * C + c];
    }
    __syncthreads();
    #pragma unroll
    for (int i = 0; i < 4; i++) {
        int ro = bx * 32 + ty + i * 8;   // original col
        int co = by * 32 + tx;           // original row
        out[(size_t)ro * R + co] = f2b(tile[tx][ty + i * 8]);
    }
}

// ---------------- mod = silu(vec) @ w_mod + b_mod (fp32) ----------------
__global__ void k_mod(const float* __restrict__ vec,
                      const float* __restrict__ w_mod,
                      const float* __restrict__ b_mod,
                      float* __restrict__ mod) {
    __shared__ float sv[HID];
    int b = blockIdx.y;
    int t = threadIdx.x;
    for (int j = t; j < HID; j += 256) {
        float v = vec[b * HID + j];
        sv[j] = v / (1.0f + expf(-v));
    }
    __syncthreads();
    int n = blockIdx.x * 256 + t;
    float acc = 0.f;
    for (int k = 0; k < HID; k++) acc += sv[k] * w_mod[(size_t)k * 3072 + n];
    mod[b * 3072 + n] = acc + b_mod[n];
}

// ---------------- x_mod = (1+scale)*layernorm(x) + shift, bf16 out ----------------
__global__ void k_lnmod(const float* __restrict__ x,
                        const float* __restrict__ mod,
                        unsigned short* __restrict__ xmod) {
    int tok = blockIdx.x;
    int t = threadIdx.x;
    int b = tok >> 11;
    float4 v4 = *(const float4*)(x + (size_t)tok * HID + t * 4);
    float v0 = v4.x, v1 = v4.y, v2 = v4.z, v3 = v4.w;
    float s  = v0 + v1 + v2 + v3;
    float sq = v0*v0 + v1*v1 + v2*v2 + v3*v3;
    for (int off = 1; off < 64; off <<= 1) {
        s  += __shfl_xor(s,  off);
        sq += __shfl_xor(sq, off);
    }
    __shared__ float ls[4], lq[4];
    int w = t >> 6;
    if ((t & 63) == 0) { ls[w] = s; lq[w] = sq; }
    __syncthreads();
    s  = ls[0] + ls[1] + ls[2] + ls[3];
    sq = lq[0] + lq[1] + lq[2] + lq[3];
    float mean = s * (1.0f / HID);
    float var  = sq * (1.0f / HID) - mean * mean;
    float rstd = rsqrtf(var + 1e-6f);
    const float* mb = mod + b * 3072;
    float y[4] = {v0, v1, v2, v3};
    unsigned short r[4];
    #pragma unroll
    for (int j = 0; j < 4; j++) {
        int col = t * 4 + j;
        float nval = (y[j] - mean) * rstd;
        r[j] = f2b((1.0f + mb[1024 + col]) * nval + mb[col]);
    }
    unsigned int o0 = (unsigned int)r[0] | ((unsigned int)r[1] << 16);
    unsigned int o1 = (unsigned int)r[2] | ((unsigned int)r[3] << 16);
    *(uint2*)(xmod + (size_t)tok * HID + t * 4) = make_uint2(o0, o1);
}

// ---------------- MFMA GEMM: C[M,N] = A[M,K](bf16) @ Bt[N,K](bf16)^T + bias(f32) ----------------
// EPI: 0 = store bf16; 1 = tanh -> bf16; 2 = out(f32) = x + gate*(acc+bias)
template<int EPI>
__global__ __launch_bounds__(256) void k_gemm(
    const unsigned short* __restrict__ A, int lda,
    const unsigned short* __restrict__ Bt, int ldb,
    const float* __restrict__ bias,
    unsigned short* __restrict__ C, float* __restrict__ Cf, int ldc,
    int K,
    const float* __restrict__ xin,
    const float* __restrict__ mod) {
    // LDS row stride 40 bf16 (80 B, 16B-aligned) -> conflict-free b128 frag reads
    __shared__ unsigned short As[128 * 40];
    __shared__ unsigned short Bs[128 * 40];
    int t = threadIdx.x;
    int bm = blockIdx.x, bn = blockIdx.y;
    int lane = t & 63, wave = t >> 6;
    int wm = (wave >> 1) * 64, wn = (wave & 1) * 64;
    int ln = lane & 15, kq = lane >> 4;

    f32x4 acc[4][4];
    #pragma unroll
    for (int i = 0; i < 4; i++)
        #pragma unroll
        for (int j = 0; j < 4; j++) acc[i][j] = {0.f, 0.f, 0.f, 0.f};

    int srow = t >> 2, skk = (t & 3) * 8;
    const unsigned short* Ab = A  + (size_t)(bm * 128) * lda;
    const unsigned short* Bb = Bt + (size_t)(bn * 128) * ldb;

    for (int k0 = 0; k0 < K; k0 += 32) {
        __syncthreads();
        #pragma unroll
        for (int p = 0; p < 2; p++) {
            int r = srow + p * 64;
            u32x4 va = *(const u32x4*)(Ab + (size_t)r * lda + k0 + skk);
            *(u32x4*)(&As[r * 40 + skk]) = va;
            u32x4 vb = *(const u32x4*)(Bb + (size_t)r * ldb + k0 + skk);
            *(u32x4*)(&Bs[r * 40 + skk]) = vb;
        }
        __syncthreads();
        bf16x8 af[4], bfr[4];
        #pragma unroll
        for (int i = 0; i < 4; i++)
            af[i] = *(const bf16x8*)(&As[(wm + i * 16 + ln) * 40 + kq * 8]);
        #pragma unroll
        for (int j = 0; j < 4; j++)
            bfr[j] = *(const bf16x8*)(&Bs[(wn + j * 16 + ln) * 40 + kq * 8]);
        #pragma unroll
        for (int i = 0; i < 4; i++)
            #pragma unroll
            for (int j = 0; j < 4; j++)
                acc[i][j] = __builtin_amdgcn_mfma_f32_16x16x32_bf16(af[i], bfr[j], acc[i][j], 0, 0, 0);
    }

    #pragma unroll
    for (int i = 0; i < 4; i++) {
        #pragma unroll
        for (int j = 0; j < 4; j++) {
            int col = bn * 128 + wn + j * 16 + ln;
            float bv = bias[col];
            #pragma unroll
            for (int r = 0; r < 4; r++) {
                int row = bm * 128 + wm + i * 16 + kq * 4 + r;
                float v = acc[i][j][r] + bv;
                if (EPI == 0) {
                    C[(size_t)row * ldc + col] = f2b(v);
                } else if (EPI == 1) {
                    C[(size_t)row * ldc + col] = f2b(tanhf(v));
                } else {
                    int b = row >> 11;
                    Cf[(size_t)row * ldc + col] =
                        xin[(size_t)row * HID + col] + mod[b * 3072 + 2048 + col] * v;
                }
            }
        }
    }
}

// ---------------- per-head RMSNorm + RoPE on q,k (in place in h, bf16) ----------------
__global__ void k_qkrope(unsigned short* __restrict__ h,
                         const float* __restrict__ pe,
                         const float* __restrict__ q_scale,
                         const float* __restrict__ k_scale) {
    int tok = blockIdx.x;
    int l = tok & (LL - 1);
    int t = threadIdx.x;
    int lane = t & 63, wave = t >> 6;
    int hh = wave * 4 + (lane >> 4);      // head 0..15
    int d0 = (lane & 15) * 4;             // 4 dims = 2 rope pairs
    unsigned short* row = h + (size_t)tok * D1;
    int i0 = d0 >> 1;
    const float* peb = pe + ((size_t)l * 32 + i0) * 4;
    float e[8];
    #pragma unroll
    for (int j = 0; j < 8; j++) e[j] = peb[j];
    #pragma unroll
    for (int qk = 0; qk < 2; qk++) {
        unsigned short* p = row + qk * HID + hh * HD + d0;
        const float* sc = (qk == 0 ? q_scale : k_scale) + d0;
        float v0 = b2f(p[0]), v1 = b2f(p[1]), v2 = b2f(p[2]), v3 = b2f(p[3]);
        float ssq = v0*v0 + v1*v1 + v2*v2 + v3*v3;
        ssq += __shfl_xor(ssq, 1, 16);
        ssq += __shfl_xor(ssq, 2, 16);
        ssq += __shfl_xor(ssq, 4, 16);
        ssq += __shfl_xor(ssq, 8, 16);
        float rr = rsqrtf(ssq * (1.0f / HD) + 1e-6f);
        v0 *= rr * sc[0];
        v1 *= rr * sc[1];
        v2 *= rr * sc[2];
        v3 *= rr * sc[3];
        float o0 = e[0]*v0 + e[1]*v1;
        float o1 = e[2]*v0 + e[3]*v1;
        float o2 = e[4]*v2 + e[5]*v3;
        float o3 = e[6]*v2 + e[7]*v3;
        p[0] = f2b(o0); p[1] = f2b(o1); p[2] = f2b(o2); p[3] = f2b(o3);
    }
}

// ---------------- attention: 4 q-rows per block, exact two-pass softmax ----------------
__global__ __launch_bounds__(256) void k_attn(const unsigned short* __restrict__ h,
                                              unsigned short* __restrict__ cat) {
    __shared__ float sc[4 * 2048];     // 32 KB scores
    __shared__ float qs[4 * 64];
    __shared__ float red[4 * 4 * 64];
    __shared__ float inv_den[4];
    int qt = blockIdx.x;               // 0..511
    int bh = blockIdx.y;               // 0..31
    int b = bh >> 4, hh = bh & 15;
    int l0 = qt * 4;
    int t = threadIdx.x;
    const unsigned short* hb = h + (size_t)b * LL * D1;

    {   // load q tile (scaled by 1/sqrt(64))
        int r = t >> 6, d = t & 63;
        qs[t] = b2f(hb[(size_t)(l0 + r) * D1 + hh * HD + d]) * 0.125f;
    }
    __syncthreads();

    // phase 1: scores
    for (int kb = 0; kb < 8; kb++) {
        int k = kb * 256 + t;
        const u32x4* kp4 = (const u32x4*)(hb + (size_t)k * D1 + HID + hh * HD);
        float kr[64];
        #pragma unroll
        for (int q8 = 0; q8 < 8; q8++) {
            u32x4 u = kp4[q8];
            #pragma unroll
            for (int w = 0; w < 4; w++) {
                unsigned int uv = u[w];
                kr[q8*8 + w*2]     = b2f((unsigned short)(uv & 0xFFFF));
                kr[q8*8 + w*2 + 1] = b2f((unsigned short)(uv >> 16));
            }
        }
        #pragma unroll
        for (int r = 0; r < 4; r++) {
            const float* q = qs + r * 64;
            float acc = 0.f;
            #pragma unroll
            for (int d = 0; d < 64; d++) acc += q[d] * kr[d];
            sc[r * 2048 + k] = acc;
        }
    }
    __syncthreads();

    // softmax: wave w owns row w
    {
        int wave = t >> 6, lane = t & 63;
        float* srow = sc + wave * 2048;
        float mx = -1e30f;
        for (int k = lane; k < 2048; k += 64) mx = fmaxf(mx, srow[k]);
        for (int off = 1; off < 64; off <<= 1) mx = fmaxf(mx, __shfl_xor(mx, off));
        float sum = 0.f;
        for (int k = lane; k < 2048; k += 64) {
            float ev = expf(srow[k] - mx);
            srow[k] = ev;
            sum += ev;
        }
        for (int off = 1; off < 64; off <<= 1) sum += __shfl_xor(sum, off);
        if (lane == 0) inv_den[wave] = 1.0f / sum;
    }
    __syncthreads();

    // phase 2: P @ V
    {
        int d = t & 63, ch = t >> 6;
        float accO[4] = {0.f, 0.f, 0.f, 0.f};
        for (int k = ch * 512; k < ch * 512 + 512; k++) {
            float vv = b2f(hb[(size_t)k * D1 + 2 * HID + hh * HD + d]);
            #pragma unroll
            for (int r = 0; r < 4; r++) accO[r] += sc[r * 2048 + k] * vv;
        }
        #pragma unroll
        for (int r = 0; r < 4; r++) red[(ch * 4 + r) * 64 + d] = accO[r];
    }
    __syncthreads();
    {
        int r = t >> 6, dd = t & 63;
        float s = red[(0*4 + r) * 64 + dd] + red[(1*4 + r) * 64 + dd]
                + red[(2*4 + r) * 64 + dd] + red[(3*4 + r) * 64 + dd];
        s *= inv_den[r];
        cat[(size_t)(b * LL + l0 + r) * DCAT + hh * HD + dd] = f2b(s);
    }
}

// ---------------- host launch ----------------
extern "C" void kernel_launch(void* const* d_in, const int* in_sizes, int n_in,
                              void* d_out, int out_size, void* d_ws, size_t ws_size,
                              hipStream_t stream) {
    const float* x       = (const float*)d_in[0];
    const float* vec     = (const float*)d_in[1];
    const float* pe      = (const float*)d_in[2];
    const float* w_mod   = (const float*)d_in[3];
    const float* b_mod   = (const float*)d_in[4];
    const float* w1      = (const float*)d_in[5];
    const float* b1      = (const float*)d_in[6];
    const float* w_mlp   = (const float*)d_in[7];
    const float* b_mlp   = (const float*)d_in[8];
    const float* w2      = (const float*)d_in[9];
    const float* b2      = (const float*)d_in[10];
    const float* q_scale = (const float*)d_in[11];
    const float* k_scale = (const float*)d_in[12];
    float* out = (float*)d_out;

    char* ws = (char*)d_ws;
    size_t off = 0;
    float* mod = (float*)(ws + off);                     off += 6144 * 4;
    unsigned short* xmod  = (unsigned short*)(ws + off); off += (size_t)TOK * HID * 2;
    unsigned short* h     = (unsigned short*)(ws + off); off += (size_t)TOK * D1 * 2;
    unsigned short* cat   = (unsigned short*)(ws + off); off += (size_t)TOK * DCAT * 2;
    unsigned short* w1T   = (unsigned short*)(ws + off); off += (size_t)D1 * HID * 2;
    unsigned short* wmlpT = (unsigned short*)(ws + off); off += (size_t)HID * MLP * 2;
    unsigned short* w2T   = (unsigned short*)(ws + off); off += (size_t)HID * DCAT * 2;

    // weight transposes+casts: [K][N] fp32 -> [N][K] bf16
    k_transpose_cvt<<<dim3(D1 / 32, HID / 32), dim3(32, 8), 0, stream>>>(w1, w1T, HID, D1);
    k_transpose_cvt<<<dim3(HID / 32, MLP / 32), dim3(32, 8), 0, stream>>>(w_mlp, wmlpT, MLP, HID);
    k_transpose_cvt<<<dim3(HID / 32, DCAT / 32), dim3(32, 8), 0, stream>>>(w2, w2T, DCAT, HID);

    k_mod<<<dim3(3072 / 256, BB), 256, 0, stream>>>(vec, w_mod, b_mod, mod);
    k_lnmod<<<TOK, 256, 0, stream>>>(x, mod, xmod);

    // h = x_mod @ w1 + b1   (M=4096, N=7168, K=1024)
    k_gemm<0><<<dim3(TOK / 128, D1 / 128), 256, 0, stream>>>(
        xmod, HID, w1T, HID, b1, h, nullptr, D1, HID, nullptr, nullptr);

    k_qkrope<<<TOK, 256, 0, stream>>>(h, pe, q_scale, k_scale);

    k_attn<<<dim3(LL / 4, BB * NH), 256, 0, stream>>>(h, cat);

    // cat[:,1024:] = tanh(h_mlp @ w_mlp + b_mlp)   (M=4096, N=1024, K=4096)
    k_gemm<1><<<dim3(TOK / 128, HID / 128), 256, 0, stream>>>(
        h + DQKV, D1, wmlpT, MLP, b_mlp, cat + HID, nullptr, DCAT, MLP, nullptr, nullptr);

    // out = x + gate * (cat @ w2 + b2)   (M=4096, N=1024, K=2048)
    k_gemm<2><<<dim3(TOK / 128, HID / 128), 256, 0, stream>>>(
        cat, DCAT, w2T, DCAT, b2, nullptr, out, HID, DCAT, x, mod);
}

// Round 3
// 553.212 us; speedup vs baseline: 7.0005x; 7.0005x over previous
//
#include <hip/hip_runtime.h>
#include <stdint.h>

// SingleStreamBlock on MI355X. fp32 in/out (per reference), bf16 MFMA compute.
// B=2 L=2048 HID=1024 NH=16 HD=64 MLP=4096.

#define HID  1024
#define NH   16
#define HD   64
#define MLP  4096
#define D1   7168   // 3*HID + MLP
#define DQKV 3072
#define DCAT 2048
#define BB   2
#define LL   2048
#define TOK  4096

typedef __attribute__((ext_vector_type(8))) short    bf16x8;
typedef __attribute__((ext_vector_type(4))) float    f32x4;
typedef __attribute__((ext_vector_type(4))) unsigned int u32x4;

__device__ __forceinline__ float b2f(unsigned short u) {
    unsigned int v = ((unsigned int)u) << 16;
    float f; __builtin_memcpy(&f, &v, 4); return f;
}
__device__ __forceinline__ unsigned short f2b(float f) {
    unsigned int v; __builtin_memcpy(&v, &f, 4);
    unsigned int r = (v + 0x7FFFu + ((v >> 16) & 1u)) >> 16;
    return (unsigned short)r;
}

// ---------------- transpose+cast: fp32 (R x C) -> bf16 (C x R) ----------------
__global__ void k_transpose_cvt(const float* __restrict__ in,
                                unsigned short* __restrict__ out, int R, int C) {
    __shared__ float tile[32][33];
    int bx = blockIdx.x, by = blockIdx.y;
    int tx = threadIdx.x, ty = threadIdx.y;   // (32,8)
    #pragma unroll
    for (int i = 0; i < 4; i++) {
        int r = by * 32 + ty + i * 8;
        int c = bx * 32 + tx;
        tile[ty + i * 8][tx] = in[(size_t)r * C + c];
    }
    __syncthreads();
    #pragma unroll
    for (int i = 0; i < 4; i++) {
        int ro = bx * 32 + ty + i * 8;   // original col
        int co = by * 32 + tx;           // original row
        out[(size_t)ro * R + co] = f2b(tile[tx][ty + i * 8]);
    }
}

// ---------------- mod = silu(vec) @ w_mod + b_mod (fp32) ----------------
__global__ void k_mod(const float* __restrict__ vec,
                      const float* __restrict__ w_mod,
                      const float* __restrict__ b_mod,
                      float* __restrict__ mod) {
    __shared__ float sv[HID];
    int b = blockIdx.y;
    int t = threadIdx.x;
    for (int j = t; j < HID; j += 256) {
        float v = vec[b * HID + j];
        sv[j] = v / (1.0f + expf(-v));
    }
    __syncthreads();
    int n = blockIdx.x * 256 + t;
    float acc = 0.f;
    for (int k = 0; k < HID; k++) acc += sv[k] * w_mod[(size_t)k * 3072 + n];
    mod[b * 3072 + n] = acc + b_mod[n];
}

// ---------------- x_mod = (1+scale)*layernorm(x) + shift, bf16 out ----------------
__global__ void k_lnmod(const float* __restrict__ x,
                        const float* __restrict__ mod,
                        unsigned short* __restrict__ xmod) {
    int tok = blockIdx.x;
    int t = threadIdx.x;
    int b = tok >> 11;
    float4 v4 = *(const float4*)(x + (size_t)tok * HID + t * 4);
    float v0 = v4.x, v1 = v4.y, v2 = v4.z, v3 = v4.w;
    float s  = v0 + v1 + v2 + v3;
    float sq = v0*v0 + v1*v1 + v2*v2 + v3*v3;
    for (int off = 1; off < 64; off <<= 1) {
        s  += __shfl_xor(s,  off);
        sq += __shfl_xor(sq, off);
    }
    __shared__ float ls[4], lq[4];
    int w = t >> 6;
    if ((t & 63) == 0) { ls[w] = s; lq[w] = sq; }
    __syncthreads();
    s  = ls[0] + ls[1] + ls[2] + ls[3];
    sq = lq[0] + lq[1] + lq[2] + lq[3];
    float mean = s * (1.0f / HID);
    float var  = sq * (1.0f / HID) - mean * mean;
    float rstd = rsqrtf(var + 1e-6f);
    const float* mb = mod + b * 3072;
    float y[4] = {v0, v1, v2, v3};
    unsigned short r[4];
    #pragma unroll
    for (int j = 0; j < 4; j++) {
        int col = t * 4 + j;
        float nval = (y[j] - mean) * rstd;
        r[j] = f2b((1.0f + mb[1024 + col]) * nval + mb[col]);
    }
    unsigned int o0 = (unsigned int)r[0] | ((unsigned int)r[1] << 16);
    unsigned int o1 = (unsigned int)r[2] | ((unsigned int)r[3] << 16);
    *(uint2*)(xmod + (size_t)tok * HID + t * 4) = make_uint2(o0, o1);
}

// ---------------- MFMA GEMM: C[M,N] = A[M,K](bf16) @ Bt[N,K](bf16)^T + bias(f32) ----------------
// EPI: 0 = store bf16; 1 = tanh -> bf16; 2 = out(f32) = x + gate*(acc+bias)
template<int EPI>
__global__ __launch_bounds__(256) void k_gemm(
    const unsigned short* __restrict__ A, int lda,
    const unsigned short* __restrict__ Bt, int ldb,
    const float* __restrict__ bias,
    unsigned short* __restrict__ C, float* __restrict__ Cf, int ldc,
    int K,
    const float* __restrict__ xin,
    const float* __restrict__ mod) {
    __shared__ unsigned short As[128 * 40];
    __shared__ unsigned short Bs[128 * 40];
    int t = threadIdx.x;
    int bm = blockIdx.x, bn = blockIdx.y;
    int lane = t & 63, wave = t >> 6;
    int wm = (wave >> 1) * 64, wn = (wave & 1) * 64;
    int ln = lane & 15, kq = lane >> 4;

    f32x4 acc[4][4];
    #pragma unroll
    for (int i = 0; i < 4; i++)
        #pragma unroll
        for (int j = 0; j < 4; j++) acc[i][j] = {0.f, 0.f, 0.f, 0.f};

    int srow = t >> 2, skk = (t & 3) * 8;
    const unsigned short* Ab = A  + (size_t)(bm * 128) * lda;
    const unsigned short* Bb = Bt + (size_t)(bn * 128) * ldb;

    for (int k0 = 0; k0 < K; k0 += 32) {
        __syncthreads();
        #pragma unroll
        for (int p = 0; p < 2; p++) {
            int r = srow + p * 64;
            u32x4 va = *(const u32x4*)(Ab + (size_t)r * lda + k0 + skk);
            *(u32x4*)(&As[r * 40 + skk]) = va;
            u32x4 vb = *(const u32x4*)(Bb + (size_t)r * ldb + k0 + skk);
            *(u32x4*)(&Bs[r * 40 + skk]) = vb;
        }
        __syncthreads();
        bf16x8 af[4], bfr[4];
        #pragma unroll
        for (int i = 0; i < 4; i++)
            af[i] = *(const bf16x8*)(&As[(wm + i * 16 + ln) * 40 + kq * 8]);
        #pragma unroll
        for (int j = 0; j < 4; j++)
            bfr[j] = *(const bf16x8*)(&Bs[(wn + j * 16 + ln) * 40 + kq * 8]);
        #pragma unroll
        for (int i = 0; i < 4; i++)
            #pragma unroll
            for (int j = 0; j < 4; j++)
                acc[i][j] = __builtin_amdgcn_mfma_f32_16x16x32_bf16(af[i], bfr[j], acc[i][j], 0, 0, 0);
    }

    #pragma unroll
    for (int i = 0; i < 4; i++) {
        #pragma unroll
        for (int j = 0; j < 4; j++) {
            int col = bn * 128 + wn + j * 16 + ln;
            float bv = bias[col];
            #pragma unroll
            for (int r = 0; r < 4; r++) {
                int row = bm * 128 + wm + i * 16 + kq * 4 + r;
                float v = acc[i][j][r] + bv;
                if (EPI == 0) {
                    C[(size_t)row * ldc + col] = f2b(v);
                } else if (EPI == 1) {
                    C[(size_t)row * ldc + col] = f2b(tanhf(v));
                } else {
                    int b = row >> 11;
                    Cf[(size_t)row * ldc + col] =
                        xin[(size_t)row * HID + col] + mod[b * 3072 + 2048 + col] * v;
                }
            }
        }
    }
}

// ---------------- per-head RMSNorm + RoPE on q,k (in place in h, bf16) ----------------
__global__ void k_qkrope(unsigned short* __restrict__ h,
                         const float* __restrict__ pe,
                         const float* __restrict__ q_scale,
                         const float* __restrict__ k_scale) {
    int tok = blockIdx.x;
    int l = tok & (LL - 1);
    int t = threadIdx.x;
    int lane = t & 63, wave = t >> 6;
    int hh = wave * 4 + (lane >> 4);      // head 0..15
    int d0 = (lane & 15) * 4;             // 4 dims = 2 rope pairs
    unsigned short* row = h + (size_t)tok * D1;
    int i0 = d0 >> 1;
    const float* peb = pe + ((size_t)l * 32 + i0) * 4;
    float e[8];
    #pragma unroll
    for (int j = 0; j < 8; j++) e[j] = peb[j];
    #pragma unroll
    for (int qk = 0; qk < 2; qk++) {
        unsigned short* p = row + qk * HID + hh * HD + d0;
        const float* sc = (qk == 0 ? q_scale : k_scale) + d0;
        float v0 = b2f(p[0]), v1 = b2f(p[1]), v2 = b2f(p[2]), v3 = b2f(p[3]);
        float ssq = v0*v0 + v1*v1 + v2*v2 + v3*v3;
        ssq += __shfl_xor(ssq, 1, 16);
        ssq += __shfl_xor(ssq, 2, 16);
        ssq += __shfl_xor(ssq, 4, 16);
        ssq += __shfl_xor(ssq, 8, 16);
        float rr = rsqrtf(ssq * (1.0f / HD) + 1e-6f);
        v0 *= rr * sc[0];
        v1 *= rr * sc[1];
        v2 *= rr * sc[2];
        v3 *= rr * sc[3];
        float o0 = e[0]*v0 + e[1]*v1;
        float o1 = e[2]*v0 + e[3]*v1;
        float o2 = e[4]*v2 + e[5]*v3;
        float o3 = e[6]*v2 + e[7]*v3;
        p[0] = f2b(o0); p[1] = f2b(o1); p[2] = f2b(o2); p[3] = f2b(o3);
    }
}

// ---------------- MFMA flash attention ----------------
// Block: 256 threads (4 waves). Each block: one (b,h), 128 Q rows (32/wave).
// S^T = K (A-operand, from LDS Ks) @ Q^T (B-operand = Q's A-layout regs).
// Online softmax in regs (quad reduce via shfl_xor 16/32).
// P -> per-wave LDS (D-layout -> B-layout), O^T = V^T (A, from transposed Vt) @ P^T.
#define KT 64            // keys per tile
#define LDP 72           // LDS row pad (bf16 elems)
__global__ __launch_bounds__(256) void k_attn(const unsigned short* __restrict__ h,
                                              unsigned short* __restrict__ cat) {
    __shared__ unsigned short Ks[KT * LDP];        // [key][d]   9216 B
    __shared__ unsigned short Vt[HD * LDP];        // [d][key]   9216 B
    __shared__ unsigned short Ps[4 * 32 * LDP];    // per-wave [q][key] 18432 B
    int t = threadIdx.x;
    int bx = blockIdx.x;               // Q tile 0..15
    int bh = blockIdx.y;               // 0..31
    int b = bh >> 4, hh = bh & 15;
    int lane = t & 63, w = t >> 6;
    int ln = lane & 15, quad = lane >> 4;
    const unsigned short* hb = h + (size_t)b * LL * D1;

    // Q fragments: qf[qt][ks] = Q[q0 + qt*16 + ln][hh*64 + ks*32 + quad*8 ..+8]
    bf16x8 qf[2][2];
    {
        const unsigned short* qbase = hb + (size_t)(bx * 128 + w * 32) * D1 + hh * HD;
        #pragma unroll
        for (int qt = 0; qt < 2; qt++)
            #pragma unroll
            for (int ks = 0; ks < 2; ks++)
                qf[qt][ks] = *(const bf16x8*)(qbase + (size_t)(qt * 16 + ln) * D1 + ks * 32 + quad * 8);
    }

    f32x4 O[4][2];                    // O^T[d=vn*16+quad*4+r][q=ln] per qt
    #pragma unroll
    for (int vn = 0; vn < 4; vn++)
        #pragma unroll
        for (int qt = 0; qt < 2; qt++) O[vn][qt] = {0.f, 0.f, 0.f, 0.f};
    float m_[2] = {-1e30f, -1e30f};
    float l_[2] = {0.f, 0.f};

    unsigned short* Psw = Ps + w * 32 * LDP;

    // staging indices
    int skey = t >> 2, sdc = (t & 3) * 16;         // K: key + 16-elem d chunk
    int p2 = (t & 31) * 2, db = (t >> 5) * 8;      // V: key pair + 8-elem d chunk

    for (int kb = 0; kb < LL / KT; kb++) {
        __syncthreads();
        {   // stage K tile [64][64] -> Ks[key][d]
            const unsigned short* kbase = hb + (size_t)(kb * KT) * D1 + HID + hh * HD;
            u32x4 ka = *(const u32x4*)(kbase + (size_t)skey * D1 + sdc);
            u32x4 kc = *(const u32x4*)(kbase + (size_t)skey * D1 + sdc + 8);
            *(u32x4*)(&Ks[skey * LDP + sdc]) = ka;
            *(u32x4*)(&Ks[skey * LDP + sdc + 8]) = kc;
            // stage V tile transposed -> Vt[d][key], pair-packed b32 writes
            const unsigned short* vbase = hb + (size_t)(kb * KT) * D1 + 2 * HID + hh * HD;
            u32x4 va = *(const u32x4*)(vbase + (size_t)p2 * D1 + db);
            u32x4 vb = *(const u32x4*)(vbase + (size_t)(p2 + 1) * D1 + db);
            #pragma unroll
            for (int j = 0; j < 8; j++) {
                unsigned int lo = (j & 1) ? (va[j >> 1] >> 16) : (va[j >> 1] & 0xFFFFu);
                unsigned int hi = (j & 1) ? (vb[j >> 1] >> 16) : (vb[j >> 1] & 0xFFFFu);
                *(unsigned int*)(&Vt[(db + j) * LDP + p2]) = lo | (hi << 16);
            }
        }
        __syncthreads();

        // S^T = K @ Q^T : st[kt][qt], D[row=key=quad*4+r][col=q=ln]
        f32x4 st[4][2];
        #pragma unroll
        for (int kt = 0; kt < 4; kt++) {
            st[kt][0] = {0.f, 0.f, 0.f, 0.f};
            st[kt][1] = {0.f, 0.f, 0.f, 0.f};
            #pragma unroll
            for (int ks = 0; ks < 2; ks++) {
                bf16x8 kf = *(const bf16x8*)(&Ks[(kt * 16 + ln) * LDP + ks * 32 + quad * 8]);
                st[kt][0] = __builtin_amdgcn_mfma_f32_16x16x32_bf16(kf, qf[0][ks], st[kt][0], 0, 0, 0);
                st[kt][1] = __builtin_amdgcn_mfma_f32_16x16x32_bf16(kf, qf[1][ks], st[kt][1], 0, 0, 0);
            }
        }

        // online softmax per qt
        #pragma unroll
        for (int qt = 0; qt < 2; qt++) {
            float p[16];
            float mx = -1e30f;
            #pragma unroll
            for (int kt = 0; kt < 4; kt++)
                #pragma unroll
                for (int r = 0; r < 4; r++) {
                    float v = st[kt][qt][r] * 0.125f;
                    p[kt * 4 + r] = v;
                    mx = fmaxf(mx, v);
                }
            mx = fmaxf(mx, __shfl_xor(mx, 16));
            mx = fmaxf(mx, __shfl_xor(mx, 32));
            float mnew = fmaxf(m_[qt], mx);
            float alpha = expf(m_[qt] - mnew);
            m_[qt] = mnew;
            float sum = 0.f;
            #pragma unroll
            for (int i = 0; i < 16; i++) {
                float e = expf(p[i] - mnew);
                p[i] = e;
                sum += e;
            }
            sum += __shfl_xor(sum, 16);
            sum += __shfl_xor(sum, 32);
            l_[qt] = l_[qt] * alpha + sum;
            #pragma unroll
            for (int vn = 0; vn < 4; vn++)
                #pragma unroll
                for (int r = 0; r < 4; r++) O[vn][qt][r] *= alpha;
            // P (bf16) -> LDS in [q][key] layout
            #pragma unroll
            for (int kt = 0; kt < 4; kt++) {
                unsigned int pa = (unsigned int)f2b(p[kt*4+0]) | ((unsigned int)f2b(p[kt*4+1]) << 16);
                unsigned int pb = (unsigned int)f2b(p[kt*4+2]) | ((unsigned int)f2b(p[kt*4+3]) << 16);
                *(unsigned int*)(&Psw[(qt * 16 + ln) * LDP + kt * 16 + quad * 4]) = pa;
                *(unsigned int*)(&Psw[(qt * 16 + ln) * LDP + kt * 16 + quad * 4 + 2]) = pb;
            }
        }

        // O^T += V^T @ P^T  (A = Vt rows, B = Ps rows; same-wave LDS, no barrier)
        #pragma unroll
        for (int kt2 = 0; kt2 < 2; kt2++) {
            bf16x8 pb0 = *(const bf16x8*)(&Psw[(0  + ln) * LDP + kt2 * 32 + quad * 8]);
            bf16x8 pb1 = *(const bf16x8*)(&Psw[(16 + ln) * LDP + kt2 * 32 + quad * 8]);
            #pragma unroll
            for (int vn = 0; vn < 4; vn++) {
                bf16x8 vf = *(const bf16x8*)(&Vt[(vn * 16 + ln) * LDP + kt2 * 32 + quad * 8]);
                O[vn][0] = __builtin_amdgcn_mfma_f32_16x16x32_bf16(vf, pb0, O[vn][0], 0, 0, 0);
                O[vn][1] = __builtin_amdgcn_mfma_f32_16x16x32_bf16(vf, pb1, O[vn][1], 0, 0, 0);
            }
        }
    }

    // epilogue: O^T[d][q] / l  -> cat[token][hh*64+d], packed b32 stores
    #pragma unroll
    for (int qt = 0; qt < 2; qt++) {
        float rl = 1.0f / l_[qt];
        size_t row = (size_t)(b * LL + bx * 128 + w * 32 + qt * 16 + ln);
        #pragma unroll
        for (int vn = 0; vn < 4; vn++) {
            #pragma unroll
            for (int r2 = 0; r2 < 4; r2 += 2) {
                unsigned int pk = (unsigned int)f2b(O[vn][qt][r2] * rl)
                                | ((unsigned int)f2b(O[vn][qt][r2 + 1] * rl) << 16);
                *(unsigned int*)(&cat[row * DCAT + hh * HD + vn * 16 + quad * 4 + r2]) = pk;
            }
        }
    }
}

// ---------------- host launch ----------------
extern "C" void kernel_launch(void* const* d_in, const int* in_sizes, int n_in,
                              void* d_out, int out_size, void* d_ws, size_t ws_size,
                              hipStream_t stream) {
    const float* x       = (const float*)d_in[0];
    const float* vec     = (const float*)d_in[1];
    const float* pe      = (const float*)d_in[2];
    const float* w_mod   = (const float*)d_in[3];
    const float* b_mod   = (const float*)d_in[4];
    const float* w1      = (const float*)d_in[5];
    const float* b1      = (const float*)d_in[6];
    const float* w_mlp   = (const float*)d_in[7];
    const float* b_mlp   = (const float*)d_in[8];
    const float* w2      = (const float*)d_in[9];
    const float* b2      = (const float*)d_in[10];
    const float* q_scale = (const float*)d_in[11];
    const float* k_scale = (const float*)d_in[12];
    float* out = (float*)d_out;

    char* ws = (char*)d_ws;
    size_t off = 0;
    float* mod = (float*)(ws + off);                     off += 6144 * 4;
    unsigned short* xmod  = (unsigned short*)(ws + off); off += (size_t)TOK * HID * 2;
    unsigned short* h     = (unsigned short*)(ws + off); off += (size_t)TOK * D1 * 2;
    unsigned short* cat   = (unsigned short*)(ws + off); off += (size_t)TOK * DCAT * 2;
    unsigned short* w1T   = (unsigned short*)(ws + off); off += (size_t)D1 * HID * 2;
    unsigned short* wmlpT = (unsigned short*)(ws + off); off += (size_t)HID * MLP * 2;
    unsigned short* w2T   = (unsigned short*)(ws + off); off += (size_t)HID * DCAT * 2;

    // weight transposes+casts: [K][N] fp32 -> [N][K] bf16
    k_transpose_cvt<<<dim3(D1 / 32, HID / 32), dim3(32, 8), 0, stream>>>(w1, w1T, HID, D1);
    k_transpose_cvt<<<dim3(HID / 32, MLP / 32), dim3(32, 8), 0, stream>>>(w_mlp, wmlpT, MLP, HID);
    k_transpose_cvt<<<dim3(HID / 32, DCAT / 32), dim3(32, 8), 0, stream>>>(w2, w2T, DCAT, HID);

    k_mod<<<dim3(3072 / 256, BB), 256, 0, stream>>>(vec, w_mod, b_mod, mod);
    k_lnmod<<<TOK, 256, 0, stream>>>(x, mod, xmod);

    // h = x_mod @ w1 + b1   (M=4096, N=7168, K=1024)
    k_gemm<0><<<dim3(TOK / 128, D1 / 128), 256, 0, stream>>>(
        xmod, HID, w1T, HID, b1, h, nullptr, D1, HID, nullptr, nullptr);

    k_qkrope<<<TOK, 256, 0, stream>>>(h, pe, q_scale, k_scale);

    k_attn<<<dim3(LL / 128, BB * NH), 256, 0, stream>>>(h, cat);

    // cat[:,1024:] = tanh(h_mlp @ w_mlp + b_mlp)   (M=4096, N=1024, K=4096)
    k_gemm<1><<<dim3(TOK / 128, HID / 128), 256, 0, stream>>>(
        h + DQKV, D1, wmlpT, MLP, b_mlp, cat + HID, nullptr, DCAT, MLP, nullptr, nullptr);

    // out = x + gate * (cat @ w2 + b2)   (M=4096, N=1024, K=2048)
    k_gemm<2><<<dim3(TOK / 128, HID / 128), 256, 0, stream>>>(
        cat, DCAT, w2T, DCAT, b2, nullptr, out, HID, DCAT, x, mod);
}

// Round 4
// 484.564 us; speedup vs baseline: 7.9922x; 1.1417x over previous
//
#include <hip/hip_runtime.h>
#include <stdint.h>

// SingleStreamBlock on MI355X. fp32 in/out (per reference), bf16 MFMA compute.
// B=2 L=2048 HID=1024 NH=16 HD=64 MLP=4096.

#define HID  1024
#define NH   16
#define HD   64
#define MLP  4096
#define D1   7168   // 3*HID + MLP
#define DQKV 3072
#define DCAT 2048
#define BB   2
#define LL   2048
#define TOK  4096

typedef __attribute__((ext_vector_type(8))) short    bf16x8;
typedef __attribute__((ext_vector_type(4))) float    f32x4;
typedef __attribute__((ext_vector_type(4))) unsigned int u32x4;

__device__ __forceinline__ float b2f(unsigned short u) {
    unsigned int v = ((unsigned int)u) << 16;
    float f; __builtin_memcpy(&f, &v, 4); return f;
}
__device__ __forceinline__ unsigned short f2b(float f) {   // RNE
    unsigned int v; __builtin_memcpy(&v, &f, 4);
    unsigned int r = (v + 0x7FFFu + ((v >> 16) & 1u)) >> 16;
    return (unsigned short)r;
}
// cheap round-to-nearest (not-even) pack of 2 floats -> 2 bf16 in a u32
__device__ __forceinline__ unsigned int pkbf2(float a, float b) {
    unsigned int ua, ub;
    __builtin_memcpy(&ua, &a, 4); __builtin_memcpy(&ub, &b, 4);
    return ((ua + 0x8000u) >> 16) | ((ub + 0x8000u) & 0xFFFF0000u);
}
// async global->LDS, 16 B per lane (dest must be wave-uniform base + lane*16)
__device__ __forceinline__ void gl_lds16(const unsigned short* g, unsigned short* l) {
    __builtin_amdgcn_global_load_lds(
        (const __attribute__((address_space(1))) unsigned int*)(g),
        (__attribute__((address_space(3))) unsigned int*)(l), 16, 0, 0);
}

// ---------------- transpose+cast: fp32 (R x C) -> bf16 (C x R) ----------------
__global__ void k_transpose_cvt(const float* __restrict__ in,
                                unsigned short* __restrict__ out, int R, int C) {
    __shared__ float tile[32][33];
    int bx = blockIdx.x, by = blockIdx.y;
    int tx = threadIdx.x, ty = threadIdx.y;   // (32,8)
    #pragma unroll
    for (int i = 0; i < 4; i++) {
        int r = by * 32 + ty + i * 8;
        int c = bx * 32 + tx;
        tile[ty + i * 8][tx] = in[(size_t)r * C + c];
    }
    __syncthreads();
    #pragma unroll
    for (int i = 0; i < 4; i++) {
        int ro = bx * 32 + ty + i * 8;   // original col
        int co = by * 32 + tx;           // original row
        out[(size_t)ro * R + co] = f2b(tile[tx][ty + i * 8]);
    }
}

// ---------------- mod = silu(vec) @ w_mod + b_mod (fp32) ----------------
// grid (96, BB): 32 outputs/block, 8 K-slices of 128 across waves
__global__ void k_mod(const float* __restrict__ vec,
                      const float* __restrict__ w_mod,
                      const float* __restrict__ b_mod,
                      float* __restrict__ mod) {
    __shared__ float sv[HID];
    __shared__ float red[8][32];
    int b = blockIdx.y, t = threadIdx.x;
    for (int j = t; j < HID; j += 256) {
        float v = vec[b * HID + j];
        sv[j] = v / (1.0f + __expf(-v));
    }
    __syncthreads();
    int n0 = blockIdx.x * 32;
    int on = t & 31, ks = t >> 5;
    float acc = 0.f;
    const float* wp = w_mod + (size_t)(ks * 128) * 3072 + n0 + on;
    #pragma unroll 4
    for (int k = 0; k < 128; k++) acc += sv[ks * 128 + k] * wp[(size_t)k * 3072];
    red[ks][on] = acc;
    __syncthreads();
    if (t < 32) {
        float s = 0.f;
        #pragma unroll
        for (int i = 0; i < 8; i++) s += red[i][t];
        mod[b * 3072 + n0 + t] = s + b_mod[n0 + t];
    }
}

// ---------------- x_mod = (1+scale)*layernorm(x) + shift, bf16 out ----------------
__global__ void k_lnmod(const float* __restrict__ x,
                        const float* __restrict__ mod,
                        unsigned short* __restrict__ xmod) {
    int tok = blockIdx.x;
    int t = threadIdx.x;
    int b = tok >> 11;
    float4 v4 = *(const float4*)(x + (size_t)tok * HID + t * 4);
    float v0 = v4.x, v1 = v4.y, v2 = v4.z, v3 = v4.w;
    float s  = v0 + v1 + v2 + v3;
    float sq = v0*v0 + v1*v1 + v2*v2 + v3*v3;
    for (int off = 1; off < 64; off <<= 1) {
        s  += __shfl_xor(s,  off);
        sq += __shfl_xor(sq, off);
    }
    __shared__ float ls[4], lq[4];
    int w = t >> 6;
    if ((t & 63) == 0) { ls[w] = s; lq[w] = sq; }
    __syncthreads();
    s  = ls[0] + ls[1] + ls[2] + ls[3];
    sq = lq[0] + lq[1] + lq[2] + lq[3];
    float mean = s * (1.0f / HID);
    float var  = sq * (1.0f / HID) - mean * mean;
    float rstd = rsqrtf(var + 1e-6f);
    const float* mb = mod + b * 3072;
    float y[4] = {v0, v1, v2, v3};
    unsigned short r[4];
    #pragma unroll
    for (int j = 0; j < 4; j++) {
        int col = t * 4 + j;
        float nval = (y[j] - mean) * rstd;
        r[j] = f2b((1.0f + mb[1024 + col]) * nval + mb[col]);
    }
    unsigned int o0 = (unsigned int)r[0] | ((unsigned int)r[1] << 16);
    unsigned int o1 = (unsigned int)r[2] | ((unsigned int)r[3] << 16);
    *(uint2*)(xmod + (size_t)tok * HID + t * 4) = make_uint2(o0, o1);
}

// ---------------- MFMA GEMM (m97-style global_load_lds staging) ----------------
// C[M,N] = A[M,K](bf16) @ Bt[N,K](bf16)^T + bias(f32)
// EPI: 0 = store bf16; 1 = tanh -> bf16; 2 = out(f32) = x + gate*(acc+bias)
template<int EPI>
__global__ __launch_bounds__(256) void k_gemm(
    const unsigned short* __restrict__ A, int lda,
    const unsigned short* __restrict__ Bt, int ldb,
    const float* __restrict__ bias,
    unsigned short* __restrict__ C, float* __restrict__ Cf, int ldc,
    int K,
    const float* __restrict__ xin,
    const float* __restrict__ mod) {
    // unpadded [128][32] tiles: b128 frag reads are conflict-free (8 lanes/4-bank group)
    __shared__ alignas(16) unsigned short As[128 * 32];
    __shared__ alignas(16) unsigned short Bs[128 * 32];
    int t = threadIdx.x;
    int bm = blockIdx.x, bn = blockIdx.y;
    int lane = t & 63, wave = t >> 6;
    int wm = (wave >> 1) * 64, wn = (wave & 1) * 64;
    int ln = lane & 15, kq = lane >> 4;

    f32x4 acc[4][4];
    #pragma unroll
    for (int i = 0; i < 4; i++)
        #pragma unroll
        for (int j = 0; j < 4; j++) acc[i][j] = {0.f, 0.f, 0.f, 0.f};

    int r0 = t >> 2, c0 = (t & 3) * 8;
    const unsigned short* Ab = A  + (size_t)(bm * 128) * lda;
    const unsigned short* Bb = Bt + (size_t)(bn * 128) * ldb;

    for (int k0 = 0; k0 < K; k0 += 32) {
        __syncthreads();
        gl_lds16(Ab + (size_t)r0 * lda + k0 + c0,        &As[t * 8]);
        gl_lds16(Ab + (size_t)(r0 + 64) * lda + k0 + c0, &As[2048 + t * 8]);
        gl_lds16(Bb + (size_t)r0 * ldb + k0 + c0,        &Bs[t * 8]);
        gl_lds16(Bb + (size_t)(r0 + 64) * ldb + k0 + c0, &Bs[2048 + t * 8]);
        __syncthreads();
        bf16x8 af[4], bfr[4];
        #pragma unroll
        for (int i = 0; i < 4; i++)
            af[i] = *(const bf16x8*)(&As[(wm + i * 16 + ln) * 32 + kq * 8]);
        #pragma unroll
        for (int j = 0; j < 4; j++)
            bfr[j] = *(const bf16x8*)(&Bs[(wn + j * 16 + ln) * 32 + kq * 8]);
        #pragma unroll
        for (int i = 0; i < 4; i++)
            #pragma unroll
            for (int j = 0; j < 4; j++)
                acc[i][j] = __builtin_amdgcn_mfma_f32_16x16x32_bf16(af[i], bfr[j], acc[i][j], 0, 0, 0);
    }

    #pragma unroll
    for (int i = 0; i < 4; i++) {
        #pragma unroll
        for (int j = 0; j < 4; j++) {
            int col = bn * 128 + wn + j * 16 + ln;
            float bv = bias[col];
            #pragma unroll
            for (int r = 0; r < 4; r++) {
                int row = bm * 128 + wm + i * 16 + kq * 4 + r;
                float v = acc[i][j][r] + bv;
                if (EPI == 0) {
                    C[(size_t)row * ldc + col] = f2b(v);
                } else if (EPI == 1) {
                    C[(size_t)row * ldc + col] = f2b(tanhf(v));
                } else {
                    int b = row >> 11;
                    Cf[(size_t)row * ldc + col] =
                        xin[(size_t)row * HID + col] + mod[b * 3072 + 2048 + col] * v;
                }
            }
        }
    }
}

// ---------------- per-head RMSNorm + RoPE on q,k (in place in h, bf16) ----------------
// q additionally pre-scaled by 0.125*log2(e) so attention softmax runs in exp2 domain.
__global__ void k_qkrope(unsigned short* __restrict__ h,
                         const float* __restrict__ pe,
                         const float* __restrict__ q_scale,
                         const float* __restrict__ k_scale) {
    int tok = blockIdx.x;
    int l = tok & (LL - 1);
    int t = threadIdx.x;
    int lane = t & 63, wave = t >> 6;
    int hh = wave * 4 + (lane >> 4);      // head 0..15
    int d0 = (lane & 15) * 4;             // 4 dims = 2 rope pairs
    unsigned short* row = h + (size_t)tok * D1;
    int i0 = d0 >> 1;
    const float* peb = pe + ((size_t)l * 32 + i0) * 4;
    float4 e0 = *(const float4*)(peb);
    float4 e1 = *(const float4*)(peb + 4);
    #pragma unroll
    for (int qk = 0; qk < 2; qk++) {
        unsigned short* p = row + qk * HID + hh * HD + d0;
        const float* sc = (qk == 0 ? q_scale : k_scale) + d0;
        uint2 qv = *(const uint2*)p;
        float v0 = b2f((unsigned short)(qv.x & 0xFFFF)), v1 = b2f((unsigned short)(qv.x >> 16));
        float v2 = b2f((unsigned short)(qv.y & 0xFFFF)), v3 = b2f((unsigned short)(qv.y >> 16));
        float ssq = v0*v0 + v1*v1 + v2*v2 + v3*v3;
        ssq += __shfl_xor(ssq, 1, 16);
        ssq += __shfl_xor(ssq, 2, 16);
        ssq += __shfl_xor(ssq, 4, 16);
        ssq += __shfl_xor(ssq, 8, 16);
        float rr = rsqrtf(ssq * (1.0f / HD) + 1e-6f);
        if (qk == 0) rr *= 0.18033688011112042f;   // 0.125 * log2(e)
        v0 *= rr * sc[0];
        v1 *= rr * sc[1];
        v2 *= rr * sc[2];
        v3 *= rr * sc[3];
        float o0 = e0.x*v0 + e0.y*v1;
        float o1 = e0.z*v0 + e0.w*v1;
        float o2 = e1.x*v2 + e1.y*v3;
        float o3 = e1.z*v2 + e1.w*v3;
        *(uint2*)p = make_uint2(pkbf2(o0, o1), pkbf2(o2, o3));
    }
}

// ---------------- MFMA flash attention (exp2 domain) ----------------
#define KT 64            // keys per tile
#define LDP 72           // LDS row pad (bf16 elems)
__global__ __launch_bounds__(256) void k_attn(const unsigned short* __restrict__ h,
                                              unsigned short* __restrict__ cat) {
    __shared__ unsigned short Ks[KT * LDP];        // [key][d]
    __shared__ unsigned short Vt[HD * LDP];        // [d][key]
    __shared__ unsigned short Ps[4 * 32 * LDP];    // per-wave [q][key]
    int t = threadIdx.x;
    int bx = blockIdx.x;               // Q tile 0..15
    int bh = blockIdx.y;               // 0..31
    int b = bh >> 4, hh = bh & 15;
    int lane = t & 63, w = t >> 6;
    int ln = lane & 15, quad = lane >> 4;
    const unsigned short* hb = h + (size_t)b * LL * D1;

    bf16x8 qf[2][2];
    {
        const unsigned short* qbase = hb + (size_t)(bx * 128 + w * 32) * D1 + hh * HD;
        #pragma unroll
        for (int qt = 0; qt < 2; qt++)
            #pragma unroll
            for (int ks = 0; ks < 2; ks++)
                qf[qt][ks] = *(const bf16x8*)(qbase + (size_t)(qt * 16 + ln) * D1 + ks * 32 + quad * 8);
    }

    f32x4 O[4][2];
    #pragma unroll
    for (int vn = 0; vn < 4; vn++)
        #pragma unroll
        for (int qt = 0; qt < 2; qt++) O[vn][qt] = {0.f, 0.f, 0.f, 0.f};
    float m_[2] = {-1e30f, -1e30f};
    float l_[2] = {0.f, 0.f};

    unsigned short* Psw = Ps + w * 32 * LDP;

    int skey = t >> 2, sdc = (t & 3) * 16;
    int p2 = (t & 31) * 2, db = (t >> 5) * 8;

    for (int kb = 0; kb < LL / KT; kb++) {
        __syncthreads();
        {   // stage K tile [64][64] -> Ks[key][d]
            const unsigned short* kbase = hb + (size_t)(kb * KT) * D1 + HID + hh * HD;
            u32x4 ka = *(const u32x4*)(kbase + (size_t)skey * D1 + sdc);
            u32x4 kc = *(const u32x4*)(kbase + (size_t)skey * D1 + sdc + 8);
            *(u32x4*)(&Ks[skey * LDP + sdc]) = ka;
            *(u32x4*)(&Ks[skey * LDP + sdc + 8]) = kc;
            // stage V tile transposed -> Vt[d][key]
            const unsigned short* vbase = hb + (size_t)(kb * KT) * D1 + 2 * HID + hh * HD;
            u32x4 va = *(const u32x4*)(vbase + (size_t)p2 * D1 + db);
            u32x4 vb = *(const u32x4*)(vbase + (size_t)(p2 + 1) * D1 + db);
            #pragma unroll
            for (int j = 0; j < 8; j++) {
                unsigned int lo = (j & 1) ? (va[j >> 1] >> 16) : (va[j >> 1] & 0xFFFFu);
                unsigned int hi = (j & 1) ? (vb[j >> 1] >> 16) : (vb[j >> 1] & 0xFFFFu);
                *(unsigned int*)(&Vt[(db + j) * LDP + p2]) = lo | (hi << 16);
            }
        }
        __syncthreads();

        // S^T = K @ Q^T
        f32x4 st[4][2];
        #pragma unroll
        for (int kt = 0; kt < 4; kt++) {
            st[kt][0] = {0.f, 0.f, 0.f, 0.f};
            st[kt][1] = {0.f, 0.f, 0.f, 0.f};
            #pragma unroll
            for (int ks = 0; ks < 2; ks++) {
                bf16x8 kf = *(const bf16x8*)(&Ks[(kt * 16 + ln) * LDP + ks * 32 + quad * 8]);
                st[kt][0] = __builtin_amdgcn_mfma_f32_16x16x32_bf16(kf, qf[0][ks], st[kt][0], 0, 0, 0);
                st[kt][1] = __builtin_amdgcn_mfma_f32_16x16x32_bf16(kf, qf[1][ks], st[kt][1], 0, 0, 0);
            }
        }

        // online softmax (exp2 domain; scores already scaled by 0.125*log2e)
        #pragma unroll
        for (int qt = 0; qt < 2; qt++) {
            float p[16];
            float mx = -1e30f;
            #pragma unroll
            for (int kt = 0; kt < 4; kt++)
                #pragma unroll
                for (int r = 0; r < 4; r++) {
                    float v = st[kt][qt][r];
                    p[kt * 4 + r] = v;
                    mx = fmaxf(mx, v);
                }
            mx = fmaxf(mx, __shfl_xor(mx, 16));
            mx = fmaxf(mx, __shfl_xor(mx, 32));
            float mnew = fmaxf(m_[qt], mx);
            float alpha = __builtin_amdgcn_exp2f(m_[qt] - mnew);
            m_[qt] = mnew;
            float sum = 0.f;
            #pragma unroll
            for (int i = 0; i < 16; i++) {
                float e = __builtin_amdgcn_exp2f(p[i] - mnew);
                p[i] = e;
                sum += e;
            }
            sum += __shfl_xor(sum, 16);
            sum += __shfl_xor(sum, 32);
            l_[qt] = l_[qt] * alpha + sum;
            #pragma unroll
            for (int vn = 0; vn < 4; vn++)
                #pragma unroll
                for (int r = 0; r < 4; r++) O[vn][qt][r] *= alpha;
            // P (bf16) -> LDS, one b64 per (qt,kt): conflict-free
            #pragma unroll
            for (int kt = 0; kt < 4; kt++) {
                unsigned long long pk =
                    (unsigned long long)pkbf2(p[kt*4+0], p[kt*4+1])
                  | ((unsigned long long)pkbf2(p[kt*4+2], p[kt*4+3]) << 32);
                *(unsigned long long*)(&Psw[(qt * 16 + ln) * LDP + kt * 16 + quad * 4]) = pk;
            }
        }

        // O^T += V^T @ P^T
        #pragma unroll
        for (int kt2 = 0; kt2 < 2; kt2++) {
            bf16x8 pb0 = *(const bf16x8*)(&Psw[(0  + ln) * LDP + kt2 * 32 + quad * 8]);
            bf16x8 pb1 = *(const bf16x8*)(&Psw[(16 + ln) * LDP + kt2 * 32 + quad * 8]);
            #pragma unroll
            for (int vn = 0; vn < 4; vn++) {
                bf16x8 vf = *(const bf16x8*)(&Vt[(vn * 16 + ln) * LDP + kt2 * 32 + quad * 8]);
                O[vn][0] = __builtin_amdgcn_mfma_f32_16x16x32_bf16(vf, pb0, O[vn][0], 0, 0, 0);
                O[vn][1] = __builtin_amdgcn_mfma_f32_16x16x32_bf16(vf, pb1, O[vn][1], 0, 0, 0);
            }
        }
    }

    // epilogue
    #pragma unroll
    for (int qt = 0; qt < 2; qt++) {
        float rl = 1.0f / l_[qt];
        size_t row = (size_t)(b * LL + bx * 128 + w * 32 + qt * 16 + ln);
        #pragma unroll
        for (int vn = 0; vn < 4; vn++) {
            #pragma unroll
            for (int r2 = 0; r2 < 4; r2 += 2) {
                unsigned int pk = pkbf2(O[vn][qt][r2] * rl, O[vn][qt][r2 + 1] * rl);
                *(unsigned int*)(&cat[row * DCAT + hh * HD + vn * 16 + quad * 4 + r2]) = pk;
            }
        }
    }
}

// ---------------- host launch ----------------
extern "C" void kernel_launch(void* const* d_in, const int* in_sizes, int n_in,
                              void* d_out, int out_size, void* d_ws, size_t ws_size,
                              hipStream_t stream) {
    const float* x       = (const float*)d_in[0];
    const float* vec     = (const float*)d_in[1];
    const float* pe      = (const float*)d_in[2];
    const float* w_mod   = (const float*)d_in[3];
    const float* b_mod   = (const float*)d_in[4];
    const float* w1      = (const float*)d_in[5];
    const float* b1      = (const float*)d_in[6];
    const float* w_mlp   = (const float*)d_in[7];
    const float* b_mlp   = (const float*)d_in[8];
    const float* w2      = (const float*)d_in[9];
    const float* b2      = (const float*)d_in[10];
    const float* q_scale = (const float*)d_in[11];
    const float* k_scale = (const float*)d_in[12];
    float* out = (float*)d_out;

    char* ws = (char*)d_ws;
    size_t off = 0;
    float* mod = (float*)(ws + off);                     off += 6144 * 4;
    unsigned short* xmod  = (unsigned short*)(ws + off); off += (size_t)TOK * HID * 2;
    unsigned short* h     = (unsigned short*)(ws + off); off += (size_t)TOK * D1 * 2;
    unsigned short* cat   = (unsigned short*)(ws + off); off += (size_t)TOK * DCAT * 2;
    unsigned short* w1T   = (unsigned short*)(ws + off); off += (size_t)D1 * HID * 2;
    unsigned short* wmlpT = (unsigned short*)(ws + off); off += (size_t)HID * MLP * 2;
    unsigned short* w2T   = (unsigned short*)(ws + off); off += (size_t)HID * DCAT * 2;

    k_transpose_cvt<<<dim3(D1 / 32, HID / 32), dim3(32, 8), 0, stream>>>(w1, w1T, HID, D1);
    k_transpose_cvt<<<dim3(HID / 32, MLP / 32), dim3(32, 8), 0, stream>>>(w_mlp, wmlpT, MLP, HID);
    k_transpose_cvt<<<dim3(HID / 32, DCAT / 32), dim3(32, 8), 0, stream>>>(w2, w2T, DCAT, HID);

    k_mod<<<dim3(96, BB), 256, 0, stream>>>(vec, w_mod, b_mod, mod);
    k_lnmod<<<TOK, 256, 0, stream>>>(x, mod, xmod);

    // h = x_mod @ w1 + b1   (M=4096, N=7168, K=1024)
    k_gemm<0><<<dim3(TOK / 128, D1 / 128), 256, 0, stream>>>(
        xmod, HID, w1T, HID, b1, h, nullptr, D1, HID, nullptr, nullptr);

    k_qkrope<<<TOK, 256, 0, stream>>>(h, pe, q_scale, k_scale);

    k_attn<<<dim3(LL / 128, BB * NH), 256, 0, stream>>>(h, cat);

    // cat[:,1024:] = tanh(h_mlp @ w_mlp + b_mlp)   (M=4096, N=1024, K=4096)
    k_gemm<1><<<dim3(TOK / 128, HID / 128), 256, 0, stream>>>(
        h + DQKV, D1, wmlpT, MLP, b_mlp, cat + HID, nullptr, DCAT, MLP, nullptr, nullptr);

    // out = x + gate * (cat @ w2 + b2)   (M=4096, N=1024, K=2048)
    k_gemm<2><<<dim3(TOK / 128, HID / 128), 256, 0, stream>>>(
        cat, DCAT, w2T, DCAT, b2, nullptr, out, HID, DCAT, x, mod);
}

// Round 5
// 447.343 us; speedup vs baseline: 8.6572x; 1.0832x over previous
//
#include <hip/hip_runtime.h>
#include <stdint.h>

// SingleStreamBlock on MI355X. fp32 in/out (per reference), bf16 MFMA compute.
// B=2 L=2048 HID=1024 NH=16 HD=64 MLP=4096.

#define HID  1024
#define NH   16
#define HD   64
#define MLP  4096
#define D1   7168   // 3*HID + MLP
#define DQKV 3072
#define DCAT 2048
#define BB   2
#define LL   2048
#define TOK  4096

typedef __attribute__((ext_vector_type(8))) short    bf16x8;
typedef __attribute__((ext_vector_type(4))) float    f32x4;
typedef __attribute__((ext_vector_type(4))) unsigned int u32x4;

__device__ __forceinline__ float b2f(unsigned short u) {
    unsigned int v = ((unsigned int)u) << 16;
    float f; __builtin_memcpy(&f, &v, 4); return f;
}
__device__ __forceinline__ unsigned short f2b(float f) {   // RNE
    unsigned int v; __builtin_memcpy(&v, &f, 4);
    unsigned int r = (v + 0x7FFFu + ((v >> 16) & 1u)) >> 16;
    return (unsigned short)r;
}
// cheap round-to-nearest pack of 2 floats -> 2 bf16 in a u32
__device__ __forceinline__ unsigned int pkbf2(float a, float b) {
    unsigned int ua, ub;
    __builtin_memcpy(&ua, &a, 4); __builtin_memcpy(&ub, &b, 4);
    return ((ua + 0x8000u) >> 16) | ((ub + 0x8000u) & 0xFFFF0000u);
}
// async global->LDS, 16 B per lane (dest is wave-uniform base + lane*16)
__device__ __forceinline__ void gl_lds16(const unsigned short* g, unsigned short* l) {
    __builtin_amdgcn_global_load_lds(
        (const __attribute__((address_space(1))) unsigned int*)(g),
        (__attribute__((address_space(3))) unsigned int*)(l), 16, 0, 0);
}

// ---------------- transpose+cast: fp32 (R x C) -> bf16 (C x R) ----------------
__global__ void k_transpose_cvt(const float* __restrict__ in,
                                unsigned short* __restrict__ out, int R, int C) {
    __shared__ float tile[32][33];
    int bx = blockIdx.x, by = blockIdx.y;
    int tx = threadIdx.x, ty = threadIdx.y;   // (32,8)
    #pragma unroll
    for (int i = 0; i < 4; i++) {
        int r = by * 32 + ty + i * 8;
        int c = bx * 32 + tx;
        tile[ty + i * 8][tx] = in[(size_t)r * C + c];
    }
    __syncthreads();
    #pragma unroll
    for (int i = 0; i < 4; i++) {
        int ro = bx * 32 + ty + i * 8;   // original col
        int co = by * 32 + tx;           // original row
        out[(size_t)ro * R + co] = f2b(tile[tx][ty + i * 8]);
    }
}

// ---------------- mod = silu(vec) @ w_mod + b_mod (fp32) ----------------
__global__ void k_mod(const float* __restrict__ vec,
                      const float* __restrict__ w_mod,
                      const float* __restrict__ b_mod,
                      float* __restrict__ mod) {
    __shared__ float sv[HID];
    __shared__ float red[8][32];
    int b = blockIdx.y, t = threadIdx.x;
    for (int j = t; j < HID; j += 256) {
        float v = vec[b * HID + j];
        sv[j] = v / (1.0f + __expf(-v));
    }
    __syncthreads();
    int n0 = blockIdx.x * 32;
    int on = t & 31, ks = t >> 5;
    float acc = 0.f;
    const float* wp = w_mod + (size_t)(ks * 128) * 3072 + n0 + on;
    #pragma unroll 4
    for (int k = 0; k < 128; k++) acc += sv[ks * 128 + k] * wp[(size_t)k * 3072];
    red[ks][on] = acc;
    __syncthreads();
    if (t < 32) {
        float s = 0.f;
        #pragma unroll
        for (int i = 0; i < 8; i++) s += red[i][t];
        mod[b * 3072 + n0 + t] = s + b_mod[n0 + t];
    }
}

// ---------------- x_mod = (1+scale)*layernorm(x) + shift, bf16 out ----------------
__global__ void k_lnmod(const float* __restrict__ x,
                        const float* __restrict__ mod,
                        unsigned short* __restrict__ xmod) {
    int tok = blockIdx.x;
    int t = threadIdx.x;
    int b = tok >> 11;
    float4 v4 = *(const float4*)(x + (size_t)tok * HID + t * 4);
    float v0 = v4.x, v1 = v4.y, v2 = v4.z, v3 = v4.w;
    float s  = v0 + v1 + v2 + v3;
    float sq = v0*v0 + v1*v1 + v2*v2 + v3*v3;
    for (int off = 1; off < 64; off <<= 1) {
        s  += __shfl_xor(s,  off);
        sq += __shfl_xor(sq, off);
    }
    __shared__ float ls[4], lq[4];
    int w = t >> 6;
    if ((t & 63) == 0) { ls[w] = s; lq[w] = sq; }
    __syncthreads();
    s  = ls[0] + ls[1] + ls[2] + ls[3];
    sq = lq[0] + lq[1] + lq[2] + lq[3];
    float mean = s * (1.0f / HID);
    float var  = sq * (1.0f / HID) - mean * mean;
    float rstd = rsqrtf(var + 1e-6f);
    const float* mb = mod + b * 3072;
    float y[4] = {v0, v1, v2, v3};
    unsigned short r[4];
    #pragma unroll
    for (int j = 0; j < 4; j++) {
        int col = t * 4 + j;
        float nval = (y[j] - mean) * rstd;
        r[j] = f2b((1.0f + mb[1024 + col]) * nval + mb[col]);
    }
    unsigned int o0 = (unsigned int)r[0] | ((unsigned int)r[1] << 16);
    unsigned int o1 = (unsigned int)r[2] | ((unsigned int)r[3] << 16);
    *(uint2*)(xmod + (size_t)tok * HID + t * 4) = make_uint2(o0, o1);
}

// ---------------- MFMA GEMM (global_load_lds staging, XOR-swizzled LDS) ----------------
// C[M,N] = A[M,K](bf16) @ Bt[N,K](bf16)^T + bias(f32)
// EPI: 0 = store bf16; 1 = tanh -> bf16; 2 = out(f32) = x + gate*(acc+bias)
// EPI: 3 = split-K fp32 partial (no bias), gridDim.z splits K, Cf = partial buffer
template<int EPI>
__global__ __launch_bounds__(256) void k_gemm(
    const unsigned short* __restrict__ A, int lda,
    const unsigned short* __restrict__ Bt, int ldb,
    const float* __restrict__ bias,
    unsigned short* __restrict__ C, float* __restrict__ Cf, int ldc,
    int K,
    const float* __restrict__ xin,
    const float* __restrict__ mod) {
    __shared__ alignas(16) unsigned short As[128 * 32];
    __shared__ alignas(16) unsigned short Bs[128 * 32];
    int t = threadIdx.x;
    int bm = blockIdx.x, bn = blockIdx.y;
    int lane = t & 63, wave = t >> 6;
    int wm = (wave >> 1) * 64, wn = (wave & 1) * 64;
    int ln = lane & 15, kq = lane >> 4;
    // swizzle: lane L stages global k-chunk (L&3)^((L>>4)&3); frag reads XOR back
    int cs  = (((t & 3) ^ ((t >> 4) & 3)) * 8);
    int kqs = (kq ^ ((ln >> 2) & 3)) * 8;

    f32x4 acc[4][4];
    #pragma unroll
    for (int i = 0; i < 4; i++)
        #pragma unroll
        for (int j = 0; j < 4; j++) acc[i][j] = {0.f, 0.f, 0.f, 0.f};

    int r0 = t >> 2;
    const unsigned short* Ab = A  + (size_t)(bm * 128) * lda;
    const unsigned short* Bb = Bt + (size_t)(bn * 128) * ldb;

    int ksplit = K / gridDim.z;
    int kbeg = blockIdx.z * ksplit, kend = kbeg + ksplit;

    for (int k0 = kbeg; k0 < kend; k0 += 32) {
        __syncthreads();
        gl_lds16(Ab + (size_t)r0 * lda + k0 + cs,        &As[t * 8]);
        gl_lds16(Ab + (size_t)(r0 + 64) * lda + k0 + cs, &As[2048 + t * 8]);
        gl_lds16(Bb + (size_t)r0 * ldb + k0 + cs,        &Bs[t * 8]);
        gl_lds16(Bb + (size_t)(r0 + 64) * ldb + k0 + cs, &Bs[2048 + t * 8]);
        __syncthreads();
        bf16x8 af[4], bfr[4];
        #pragma unroll
        for (int i = 0; i < 4; i++)
            af[i] = *(const bf16x8*)(&As[(wm + i * 16 + ln) * 32 + kqs]);
        #pragma unroll
        for (int j = 0; j < 4; j++)
            bfr[j] = *(const bf16x8*)(&Bs[(wn + j * 16 + ln) * 32 + kqs]);
        #pragma unroll
        for (int i = 0; i < 4; i++)
            #pragma unroll
            for (int j = 0; j < 4; j++)
                acc[i][j] = __builtin_amdgcn_mfma_f32_16x16x32_bf16(af[i], bfr[j], acc[i][j], 0, 0, 0);
    }

    #pragma unroll
    for (int i = 0; i < 4; i++) {
        #pragma unroll
        for (int j = 0; j < 4; j++) {
            int col = bn * 128 + wn + j * 16 + ln;
            float bv = (EPI == 3) ? 0.f : bias[col];
            #pragma unroll
            for (int r = 0; r < 4; r++) {
                int row = bm * 128 + wm + i * 16 + kq * 4 + r;
                float v = acc[i][j][r] + bv;
                if (EPI == 0) {
                    C[(size_t)row * ldc + col] = f2b(v);
                } else if (EPI == 1) {
                    C[(size_t)row * ldc + col] = f2b(tanhf(v));
                } else if (EPI == 2) {
                    int b = row >> 11;
                    Cf[(size_t)row * ldc + col] =
                        xin[(size_t)row * HID + col] + mod[b * 3072 + 2048 + col] * v;
                } else {
                    Cf[((size_t)blockIdx.z * TOK + row) * ldc + col] = v;
                }
            }
        }
    }
}

// ---------------- split-K reduce 1: cat[:,1024:] = tanh(p0+p1+bias) ----------------
__global__ __launch_bounds__(256) void k_red1(const float* __restrict__ part,
                                              const float* __restrict__ bias,
                                              unsigned short* __restrict__ cat) {
    int idx = blockIdx.x * 256 + threadIdx.x;
    int row = idx >> 8;
    int c4  = (idx & 255) * 4;
    float4 p0 = *(const float4*)(part + (size_t)row * HID + c4);
    float4 p1 = *(const float4*)(part + ((size_t)TOK + row) * HID + c4);
    float4 bv = *(const float4*)(bias + c4);
    float a0 = tanhf(p0.x + p1.x + bv.x);
    float a1 = tanhf(p0.y + p1.y + bv.y);
    float a2 = tanhf(p0.z + p1.z + bv.z);
    float a3 = tanhf(p0.w + p1.w + bv.w);
    *(uint2*)(&cat[(size_t)row * DCAT + HID + c4]) =
        make_uint2(pkbf2(a0, a1), pkbf2(a2, a3));
}

// ---------------- split-K reduce 2: out = x + gate*(p0+p1+bias) (fp32) ----------------
__global__ __launch_bounds__(256) void k_red2(const float* __restrict__ part,
                                              const float* __restrict__ bias,
                                              const float* __restrict__ x,
                                              const float* __restrict__ mod,
                                              float* __restrict__ out) {
    int idx = blockIdx.x * 256 + threadIdx.x;
    int row = idx >> 8;
    int c4  = (idx & 255) * 4;
    int b = row >> 11;
    float4 p0 = *(const float4*)(part + (size_t)row * HID + c4);
    float4 p1 = *(const float4*)(part + ((size_t)TOK + row) * HID + c4);
    float4 bv = *(const float4*)(bias + c4);
    float4 gv = *(const float4*)(mod + b * 3072 + 2048 + c4);
    float4 xv = *(const float4*)(x + (size_t)row * HID + c4);
    float4 o;
    o.x = xv.x + gv.x * (p0.x + p1.x + bv.x);
    o.y = xv.y + gv.y * (p0.y + p1.y + bv.y);
    o.z = xv.z + gv.z * (p0.z + p1.z + bv.z);
    o.w = xv.w + gv.w * (p0.w + p1.w + bv.w);
    *(float4*)(out + (size_t)row * HID + c4) = o;
}

// ---------------- per-head RMSNorm + RoPE on q,k (in place in h, bf16) ----------------
// q additionally pre-scaled by 0.125*log2(e) so attention softmax runs in exp2 domain.
__global__ void k_qkrope(unsigned short* __restrict__ h,
                         const float* __restrict__ pe,
                         const float* __restrict__ q_scale,
                         const float* __restrict__ k_scale) {
    int tok = blockIdx.x;
    int l = tok & (LL - 1);
    int t = threadIdx.x;
    int lane = t & 63, wave = t >> 6;
    int hh = wave * 4 + (lane >> 4);      // head 0..15
    int d0 = (lane & 15) * 4;             // 4 dims = 2 rope pairs
    unsigned short* row = h + (size_t)tok * D1;
    int i0 = d0 >> 1;
    const float* peb = pe + ((size_t)l * 32 + i0) * 4;
    float4 e0 = *(const float4*)(peb);
    float4 e1 = *(const float4*)(peb + 4);
    #pragma unroll
    for (int qk = 0; qk < 2; qk++) {
        unsigned short* p = row + qk * HID + hh * HD + d0;
        const float* sc = (qk == 0 ? q_scale : k_scale) + d0;
        uint2 qv = *(const uint2*)p;
        float v0 = b2f((unsigned short)(qv.x & 0xFFFF)), v1 = b2f((unsigned short)(qv.x >> 16));
        float v2 = b2f((unsigned short)(qv.y & 0xFFFF)), v3 = b2f((unsigned short)(qv.y >> 16));
        float ssq = v0*v0 + v1*v1 + v2*v2 + v3*v3;
        ssq += __shfl_xor(ssq, 1, 16);
        ssq += __shfl_xor(ssq, 2, 16);
        ssq += __shfl_xor(ssq, 4, 16);
        ssq += __shfl_xor(ssq, 8, 16);
        float rr = rsqrtf(ssq * (1.0f / HD) + 1e-6f);
        if (qk == 0) rr *= 0.18033688011112042f;   // 0.125 * log2(e)
        v0 *= rr * sc[0];
        v1 *= rr * sc[1];
        v2 *= rr * sc[2];
        v3 *= rr * sc[3];
        float o0 = e0.x*v0 + e0.y*v1;
        float o1 = e0.z*v0 + e0.w*v1;
        float o2 = e1.x*v2 + e1.y*v3;
        float o3 = e1.z*v2 + e1.w*v3;
        *(uint2*)p = make_uint2(pkbf2(o0, o1), pkbf2(o2, o3));
    }
}

// ---------------- MFMA flash attention (exp2 domain) ----------------
#define KT 64            // keys per tile
#define LDP 72           // LDS row pad (bf16 elems)
__global__ __launch_bounds__(256) void k_attn(const unsigned short* __restrict__ h,
                                              unsigned short* __restrict__ cat) {
    __shared__ unsigned short Ks[KT * LDP];        // [key][d]
    __shared__ unsigned short Vt[HD * LDP];        // [d][key]
    __shared__ unsigned short Ps[4 * 32 * LDP];    // per-wave [q][key]
    int t = threadIdx.x;
    int bx = blockIdx.x;               // Q tile 0..15
    int bh = blockIdx.y;               // 0..31
    int b = bh >> 4, hh = bh & 15;
    int lane = t & 63, w = t >> 6;
    int ln = lane & 15, quad = lane >> 4;
    const unsigned short* hb = h + (size_t)b * LL * D1;

    bf16x8 qf[2][2];
    {
        const unsigned short* qbase = hb + (size_t)(bx * 128 + w * 32) * D1 + hh * HD;
        #pragma unroll
        for (int qt = 0; qt < 2; qt++)
            #pragma unroll
            for (int ks = 0; ks < 2; ks++)
                qf[qt][ks] = *(const bf16x8*)(qbase + (size_t)(qt * 16 + ln) * D1 + ks * 32 + quad * 8);
    }

    f32x4 O[4][2];
    #pragma unroll
    for (int vn = 0; vn < 4; vn++)
        #pragma unroll
        for (int qt = 0; qt < 2; qt++) O[vn][qt] = {0.f, 0.f, 0.f, 0.f};
    float m_[2] = {-1e30f, -1e30f};
    float l_[2] = {0.f, 0.f};

    unsigned short* Psw = Ps + w * 32 * LDP;

    int skey = t >> 2, sdc = (t & 3) * 16;
    int p2 = (t & 31) * 2, db = (t >> 5) * 8;

    for (int kb = 0; kb < LL / KT; kb++) {
        __syncthreads();
        {   // stage K tile [64][64] -> Ks[key][d]
            const unsigned short* kbase = hb + (size_t)(kb * KT) * D1 + HID + hh * HD;
            u32x4 ka = *(const u32x4*)(kbase + (size_t)skey * D1 + sdc);
            u32x4 kc = *(const u32x4*)(kbase + (size_t)skey * D1 + sdc + 8);
            *(u32x4*)(&Ks[skey * LDP + sdc]) = ka;
            *(u32x4*)(&Ks[skey * LDP + sdc + 8]) = kc;
            // stage V tile transposed -> Vt[d][key]
            const unsigned short* vbase = hb + (size_t)(kb * KT) * D1 + 2 * HID + hh * HD;
            u32x4 va = *(const u32x4*)(vbase + (size_t)p2 * D1 + db);
            u32x4 vb = *(const u32x4*)(vbase + (size_t)(p2 + 1) * D1 + db);
            #pragma unroll
            for (int j = 0; j < 8; j++) {
                unsigned int lo = (j & 1) ? (va[j >> 1] >> 16) : (va[j >> 1] & 0xFFFFu);
                unsigned int hi = (j & 1) ? (vb[j >> 1] >> 16) : (vb[j >> 1] & 0xFFFFu);
                *(unsigned int*)(&Vt[(db + j) * LDP + p2]) = lo | (hi << 16);
            }
        }
        __syncthreads();

        // S^T = K @ Q^T
        f32x4 st[4][2];
        #pragma unroll
        for (int kt = 0; kt < 4; kt++) {
            st[kt][0] = {0.f, 0.f, 0.f, 0.f};
            st[kt][1] = {0.f, 0.f, 0.f, 0.f};
            #pragma unroll
            for (int ks = 0; ks < 2; ks++) {
                bf16x8 kf = *(const bf16x8*)(&Ks[(kt * 16 + ln) * LDP + ks * 32 + quad * 8]);
                st[kt][0] = __builtin_amdgcn_mfma_f32_16x16x32_bf16(kf, qf[0][ks], st[kt][0], 0, 0, 0);
                st[kt][1] = __builtin_amdgcn_mfma_f32_16x16x32_bf16(kf, qf[1][ks], st[kt][1], 0, 0, 0);
            }
        }

        // online softmax (exp2 domain; scores already scaled by 0.125*log2e)
        #pragma unroll
        for (int qt = 0; qt < 2; qt++) {
            float p[16];
            float mx = -1e30f;
            #pragma unroll
            for (int kt = 0; kt < 4; kt++)
                #pragma unroll
                for (int r = 0; r < 4; r++) {
                    float v = st[kt][qt][r];
                    p[kt * 4 + r] = v;
                    mx = fmaxf(mx, v);
                }
            mx = fmaxf(mx, __shfl_xor(mx, 16));
            mx = fmaxf(mx, __shfl_xor(mx, 32));
            float mnew = fmaxf(m_[qt], mx);
            float alpha = __builtin_amdgcn_exp2f(m_[qt] - mnew);
            m_[qt] = mnew;
            float sum = 0.f;
            #pragma unroll
            for (int i = 0; i < 16; i++) {
                float e = __builtin_amdgcn_exp2f(p[i] - mnew);
                p[i] = e;
                sum += e;
            }
            sum += __shfl_xor(sum, 16);
            sum += __shfl_xor(sum, 32);
            l_[qt] = l_[qt] * alpha + sum;
            #pragma unroll
            for (int vn = 0; vn < 4; vn++)
                #pragma unroll
                for (int r = 0; r < 4; r++) O[vn][qt][r] *= alpha;
            #pragma unroll
            for (int kt = 0; kt < 4; kt++) {
                unsigned long long pk =
                    (unsigned long long)pkbf2(p[kt*4+0], p[kt*4+1])
                  | ((unsigned long long)pkbf2(p[kt*4+2], p[kt*4+3]) << 32);
                *(unsigned long long*)(&Psw[(qt * 16 + ln) * LDP + kt * 16 + quad * 4]) = pk;
            }
        }

        // O^T += V^T @ P^T
        #pragma unroll
        for (int kt2 = 0; kt2 < 2; kt2++) {
            bf16x8 pb0 = *(const bf16x8*)(&Psw[(0  + ln) * LDP + kt2 * 32 + quad * 8]);
            bf16x8 pb1 = *(const bf16x8*)(&Psw[(16 + ln) * LDP + kt2 * 32 + quad * 8]);
            #pragma unroll
            for (int vn = 0; vn < 4; vn++) {
                bf16x8 vf = *(const bf16x8*)(&Vt[(vn * 16 + ln) * LDP + kt2 * 32 + quad * 8]);
                O[vn][0] = __builtin_amdgcn_mfma_f32_16x16x32_bf16(vf, pb0, O[vn][0], 0, 0, 0);
                O[vn][1] = __builtin_amdgcn_mfma_f32_16x16x32_bf16(vf, pb1, O[vn][1], 0, 0, 0);
            }
        }
    }

    // epilogue
    #pragma unroll
    for (int qt = 0; qt < 2; qt++) {
        float rl = 1.0f / l_[qt];
        size_t row = (size_t)(b * LL + bx * 128 + w * 32 + qt * 16 + ln);
        #pragma unroll
        for (int vn = 0; vn < 4; vn++) {
            #pragma unroll
            for (int r2 = 0; r2 < 4; r2 += 2) {
                unsigned int pk = pkbf2(O[vn][qt][r2] * rl, O[vn][qt][r2 + 1] * rl);
                *(unsigned int*)(&cat[row * DCAT + hh * HD + vn * 16 + quad * 4 + r2]) = pk;
            }
        }
    }
}

// ---------------- host launch ----------------
extern "C" void kernel_launch(void* const* d_in, const int* in_sizes, int n_in,
                              void* d_out, int out_size, void* d_ws, size_t ws_size,
                              hipStream_t stream) {
    const float* x       = (const float*)d_in[0];
    const float* vec     = (const float*)d_in[1];
    const float* pe      = (const float*)d_in[2];
    const float* w_mod   = (const float*)d_in[3];
    const float* b_mod   = (const float*)d_in[4];
    const float* w1      = (const float*)d_in[5];
    const float* b1      = (const float*)d_in[6];
    const float* w_mlp   = (const float*)d_in[7];
    const float* b_mlp   = (const float*)d_in[8];
    const float* w2      = (const float*)d_in[9];
    const float* b2      = (const float*)d_in[10];
    const float* q_scale = (const float*)d_in[11];
    const float* k_scale = (const float*)d_in[12];
    float* out = (float*)d_out;

    char* ws = (char*)d_ws;
    size_t off = 0;
    float* mod = (float*)(ws + off);                     off += 6144 * 4;
    unsigned short* xmod  = (unsigned short*)(ws + off); off += (size_t)TOK * HID * 2;
    unsigned short* h     = (unsigned short*)(ws + off); off += (size_t)TOK * D1 * 2;
    unsigned short* cat   = (unsigned short*)(ws + off); off += (size_t)TOK * DCAT * 2;
    unsigned short* w1T   = (unsigned short*)(ws + off); off += (size_t)D1 * HID * 2;
    unsigned short* wmlpT = (unsigned short*)(ws + off); off += (size_t)HID * MLP * 2;
    unsigned short* w2T   = (unsigned short*)(ws + off); off += (size_t)HID * DCAT * 2;
    float* part = (float*)(ws + off);                    off += (size_t)2 * TOK * HID * 4;

    k_transpose_cvt<<<dim3(D1 / 32, HID / 32), dim3(32, 8), 0, stream>>>(w1, w1T, HID, D1);
    k_transpose_cvt<<<dim3(HID / 32, MLP / 32), dim3(32, 8), 0, stream>>>(w_mlp, wmlpT, MLP, HID);
    k_transpose_cvt<<<dim3(HID / 32, DCAT / 32), dim3(32, 8), 0, stream>>>(w2, w2T, DCAT, HID);

    k_mod<<<dim3(96, BB), 256, 0, stream>>>(vec, w_mod, b_mod, mod);
    k_lnmod<<<TOK, 256, 0, stream>>>(x, mod, xmod);

    // h = x_mod @ w1 + b1   (M=4096, N=7168, K=1024)
    k_gemm<0><<<dim3(TOK / 128, D1 / 128), 256, 0, stream>>>(
        xmod, HID, w1T, HID, b1, h, nullptr, D1, HID, nullptr, nullptr);

    k_qkrope<<<TOK, 256, 0, stream>>>(h, pe, q_scale, k_scale);

    k_attn<<<dim3(LL / 128, BB * NH), 256, 0, stream>>>(h, cat);

    // mlp partials: h_mlp @ w_mlp   (M=4096, N=1024, K=4096, split-K=2)
    k_gemm<3><<<dim3(TOK / 128, HID / 128, 2), 256, 0, stream>>>(
        h + DQKV, D1, wmlpT, MLP, b_mlp, nullptr, part, HID, MLP, nullptr, nullptr);
    k_red1<<<TOK * HID / 1024, 256, 0, stream>>>(part, b_mlp, cat);

    // out partials: cat @ w2   (M=4096, N=1024, K=2048, split-K=2)
    k_gemm<3><<<dim3(TOK / 128, HID / 128, 2), 256, 0, stream>>>(
        cat, DCAT, w2T, DCAT, b2, nullptr, part, HID, DCAT, nullptr, nullptr);
    k_red2<<<TOK * HID / 1024, 256, 0, stream>>>(part, b2, x, mod, out);
}

// Round 6
// 417.990 us; speedup vs baseline: 9.2651x; 1.0702x over previous
//
#include <hip/hip_runtime.h>
#include <stdint.h>

// SingleStreamBlock on MI355X. fp32 in/out (per reference), bf16 MFMA compute.
// B=2 L=2048 HID=1024 NH=16 HD=64 MLP=4096.

#define HID  1024
#define NH   16
#define HD   64
#define MLP  4096
#define D1   7168   // 3*HID + MLP
#define DQKV 3072
#define DCAT 2048
#define BB   2
#define LL   2048
#define TOK  4096

typedef __attribute__((ext_vector_type(8))) short    bf16x8;
typedef __attribute__((ext_vector_type(4))) float    f32x4;
typedef __attribute__((ext_vector_type(4))) unsigned int u32x4;

__device__ __forceinline__ float b2f(unsigned short u) {
    unsigned int v = ((unsigned int)u) << 16;
    float f; __builtin_memcpy(&f, &v, 4); return f;
}
__device__ __forceinline__ unsigned short f2b(float f) {   // RNE
    unsigned int v; __builtin_memcpy(&v, &f, 4);
    unsigned int r = (v + 0x7FFFu + ((v >> 16) & 1u)) >> 16;
    return (unsigned short)r;
}
// cheap round-to-nearest pack of 2 floats -> 2 bf16 in a u32
__device__ __forceinline__ unsigned int pkbf2(float a, float b) {
    unsigned int ua, ub;
    __builtin_memcpy(&ua, &a, 4); __builtin_memcpy(&ub, &b, 4);
    return ((ua + 0x8000u) >> 16) | ((ub + 0x8000u) & 0xFFFF0000u);
}
// async global->LDS, 16 B per lane (dest is wave-uniform base + lane*16)
__device__ __forceinline__ void gl_lds16(const unsigned short* g, unsigned short* l) {
    __builtin_amdgcn_global_load_lds(
        (const __attribute__((address_space(1))) unsigned int*)(g),
        (__attribute__((address_space(3))) unsigned int*)(l), 16, 0, 0);
}

// ---------------- transpose+cast: fp32 (R x C) -> bf16 (C x R) ----------------
__global__ void k_transpose_cvt(const float* __restrict__ in,
                                unsigned short* __restrict__ out, int R, int C) {
    __shared__ float tile[32][33];
    int bx = blockIdx.x, by = blockIdx.y;
    int tx = threadIdx.x, ty = threadIdx.y;   // (32,8)
    #pragma unroll
    for (int i = 0; i < 4; i++) {
        int r = by * 32 + ty + i * 8;
        int c = bx * 32 + tx;
        tile[ty + i * 8][tx] = in[(size_t)r * C + c];
    }
    __syncthreads();
    #pragma unroll
    for (int i = 0; i < 4; i++) {
        int ro = bx * 32 + ty + i * 8;   // original col
        int co = by * 32 + tx;           // original row
        out[(size_t)ro * R + co] = f2b(tile[tx][ty + i * 8]);
    }
}

// ---------------- mod = silu(vec) @ w_mod + b_mod (fp32) ----------------
__global__ void k_mod(const float* __restrict__ vec,
                      const float* __restrict__ w_mod,
                      const float* __restrict__ b_mod,
                      float* __restrict__ mod) {
    __shared__ float sv[HID];
    __shared__ float red[8][32];
    int b = blockIdx.y, t = threadIdx.x;
    for (int j = t; j < HID; j += 256) {
        float v = vec[b * HID + j];
        sv[j] = v / (1.0f + __expf(-v));
    }
    __syncthreads();
    int n0 = blockIdx.x * 32;
    int on = t & 31, ks = t >> 5;
    float acc = 0.f;
    const float* wp = w_mod + (size_t)(ks * 128) * 3072 + n0 + on;
    #pragma unroll 4
    for (int k = 0; k < 128; k++) acc += sv[ks * 128 + k] * wp[(size_t)k * 3072];
    red[ks][on] = acc;
    __syncthreads();
    if (t < 32) {
        float s = 0.f;
        #pragma unroll
        for (int i = 0; i < 8; i++) s += red[i][t];
        mod[b * 3072 + n0 + t] = s + b_mod[n0 + t];
    }
}

// ---------------- x_mod = (1+scale)*layernorm(x) + shift, bf16 out ----------------
__global__ void k_lnmod(const float* __restrict__ x,
                        const float* __restrict__ mod,
                        unsigned short* __restrict__ xmod) {
    int tok = blockIdx.x;
    int t = threadIdx.x;
    int b = tok >> 11;
    float4 v4 = *(const float4*)(x + (size_t)tok * HID + t * 4);
    float v0 = v4.x, v1 = v4.y, v2 = v4.z, v3 = v4.w;
    float s  = v0 + v1 + v2 + v3;
    float sq = v0*v0 + v1*v1 + v2*v2 + v3*v3;
    for (int off = 1; off < 64; off <<= 1) {
        s  += __shfl_xor(s,  off);
        sq += __shfl_xor(sq, off);
    }
    __shared__ float ls[4], lq[4];
    int w = t >> 6;
    if ((t & 63) == 0) { ls[w] = s; lq[w] = sq; }
    __syncthreads();
    s  = ls[0] + ls[1] + ls[2] + ls[3];
    sq = lq[0] + lq[1] + lq[2] + lq[3];
    float mean = s * (1.0f / HID);
    float var  = sq * (1.0f / HID) - mean * mean;
    float rstd = rsqrtf(var + 1e-6f);
    const float* mb = mod + b * 3072;
    float y[4] = {v0, v1, v2, v3};
    unsigned short r[4];
    #pragma unroll
    for (int j = 0; j < 4; j++) {
        int col = t * 4 + j;
        float nval = (y[j] - mean) * rstd;
        r[j] = f2b((1.0f + mb[1024 + col]) * nval + mb[col]);
    }
    unsigned int o0 = (unsigned int)r[0] | ((unsigned int)r[1] << 16);
    unsigned int o1 = (unsigned int)r[2] | ((unsigned int)r[3] << 16);
    *(uint2*)(xmod + (size_t)tok * HID + t * 4) = make_uint2(o0, o1);
}

// ---------------- MFMA GEMM (BK=64, global_load_lds staging, XOR-8 swizzle) ----------------
// C[M,N] = A[M,K](bf16) @ Bt[N,K](bf16)^T + bias(f32)
// EPI: 0 = store bf16; 1 = tanh -> bf16; 2 = out(f32) = x + gate*(acc+bias)
// EPI: 3 = split-K fp32 partial (no bias), gridDim.z splits K, Cf = partial buffer
template<int EPI>
__global__ __launch_bounds__(256) void k_gemm(
    const unsigned short* __restrict__ A, int lda,
    const unsigned short* __restrict__ Bt, int ldb,
    const float* __restrict__ bias,
    unsigned short* __restrict__ C, float* __restrict__ Cf, int ldc,
    int K,
    const float* __restrict__ xin,
    const float* __restrict__ mod) {
    // [128][64] tiles. Row = 128 B = full bank wrap, so chunk slots are
    // XOR-8 swizzled: slot = global_chunk ^ (row & 7)  -> balanced b128 reads.
    __shared__ alignas(16) unsigned short As[128 * 64];
    __shared__ alignas(16) unsigned short Bs[128 * 64];
    int t = threadIdx.x;
    int bm = blockIdx.x, bn = blockIdx.y;
    int lane = t & 63, wave = t >> 6;
    int wm = (wave >> 1) * 64, wn = (wave & 1) * 64;
    int ln = lane & 15, kq = lane >> 4;
    int ln7 = ln & 7;

    f32x4 acc[4][4];
    #pragma unroll
    for (int i = 0; i < 4; i++)
        #pragma unroll
        for (int j = 0; j < 4; j++) acc[i][j] = {0.f, 0.f, 0.f, 0.f};

    int sr  = t >> 3;                    // staging row 0..31 (per 32-row group)
    int scg = (t & 7) ^ (sr & 7);        // global chunk fetched by this lane
    const unsigned short* Ab = A  + (size_t)(bm * 128) * lda;
    const unsigned short* Bb = Bt + (size_t)(bn * 128) * ldb;

    int ksplit = K / gridDim.z;
    int kbeg = blockIdx.z * ksplit, kend = kbeg + ksplit;

    for (int k0 = kbeg; k0 < kend; k0 += 64) {
        __syncthreads();
        #pragma unroll
        for (int c = 0; c < 4; c++) {
            gl_lds16(Ab + (size_t)(c * 32 + sr) * lda + k0 + scg * 8, &As[c * 2048 + t * 8]);
            gl_lds16(Bb + (size_t)(c * 32 + sr) * ldb + k0 + scg * 8, &Bs[c * 2048 + t * 8]);
        }
        __syncthreads();
        #pragma unroll
        for (int ks = 0; ks < 2; ks++) {
            int slot = ((ks * 4 + kq) ^ ln7) * 8;
            bf16x8 af[4], bfr[4];
            #pragma unroll
            for (int i = 0; i < 4; i++)
                af[i] = *(const bf16x8*)(&As[(wm + i * 16 + ln) * 64 + slot]);
            #pragma unroll
            for (int j = 0; j < 4; j++)
                bfr[j] = *(const bf16x8*)(&Bs[(wn + j * 16 + ln) * 64 + slot]);
            #pragma unroll
            for (int i = 0; i < 4; i++)
                #pragma unroll
                for (int j = 0; j < 4; j++)
                    acc[i][j] = __builtin_amdgcn_mfma_f32_16x16x32_bf16(af[i], bfr[j], acc[i][j], 0, 0, 0);
        }
    }

    #pragma unroll
    for (int i = 0; i < 4; i++) {
        #pragma unroll
        for (int j = 0; j < 4; j++) {
            int col = bn * 128 + wn + j * 16 + ln;
            float bv = (EPI == 3) ? 0.f : bias[col];
            #pragma unroll
            for (int r = 0; r < 4; r++) {
                int row = bm * 128 + wm + i * 16 + kq * 4 + r;
                float v = acc[i][j][r] + bv;
                if (EPI == 0) {
                    C[(size_t)row * ldc + col] = f2b(v);
                } else if (EPI == 1) {
                    C[(size_t)row * ldc + col] = f2b(tanhf(v));
                } else if (EPI == 2) {
                    int b = row >> 11;
                    Cf[(size_t)row * ldc + col] =
                        xin[(size_t)row * HID + col] + mod[b * 3072 + 2048 + col] * v;
                } else {
                    Cf[((size_t)blockIdx.z * TOK + row) * ldc + col] = v;
                }
            }
        }
    }
}

// ---------------- split-K reduce 1: cat[:,1024:] = tanh(p0+p1+bias) ----------------
__global__ __launch_bounds__(256) void k_red1(const float* __restrict__ part,
                                              const float* __restrict__ bias,
                                              unsigned short* __restrict__ cat) {
    int idx = blockIdx.x * 256 + threadIdx.x;
    int row = idx >> 8;
    int c4  = (idx & 255) * 4;
    float4 p0 = *(const float4*)(part + (size_t)row * HID + c4);
    float4 p1 = *(const float4*)(part + ((size_t)TOK + row) * HID + c4);
    float4 bv = *(const float4*)(bias + c4);
    float a0 = tanhf(p0.x + p1.x + bv.x);
    float a1 = tanhf(p0.y + p1.y + bv.y);
    float a2 = tanhf(p0.z + p1.z + bv.z);
    float a3 = tanhf(p0.w + p1.w + bv.w);
    *(uint2*)(&cat[(size_t)row * DCAT + HID + c4]) =
        make_uint2(pkbf2(a0, a1), pkbf2(a2, a3));
}

// ---------------- split-K reduce 2: out = x + gate*(p0+p1+bias) (fp32) ----------------
__global__ __launch_bounds__(256) void k_red2(const float* __restrict__ part,
                                              const float* __restrict__ bias,
                                              const float* __restrict__ x,
                                              const float* __restrict__ mod,
                                              float* __restrict__ out) {
    int idx = blockIdx.x * 256 + threadIdx.x;
    int row = idx >> 8;
    int c4  = (idx & 255) * 4;
    int b = row >> 11;
    float4 p0 = *(const float4*)(part + (size_t)row * HID + c4);
    float4 p1 = *(const float4*)(part + ((size_t)TOK + row) * HID + c4);
    float4 bv = *(const float4*)(bias + c4);
    float4 gv = *(const float4*)(mod + b * 3072 + 2048 + c4);
    float4 xv = *(const float4*)(x + (size_t)row * HID + c4);
    float4 o;
    o.x = xv.x + gv.x * (p0.x + p1.x + bv.x);
    o.y = xv.y + gv.y * (p0.y + p1.y + bv.y);
    o.z = xv.z + gv.z * (p0.z + p1.z + bv.z);
    o.w = xv.w + gv.w * (p0.w + p1.w + bv.w);
    *(float4*)(out + (size_t)row * HID + c4) = o;
}

// ---------------- per-head RMSNorm + RoPE on q,k (in place in h, bf16) ----------------
// q additionally pre-scaled by 0.125*log2(e) so attention softmax runs in exp2 domain.
__global__ void k_qkrope(unsigned short* __restrict__ h,
                         const float* __restrict__ pe,
                         const float* __restrict__ q_scale,
                         const float* __restrict__ k_scale) {
    int tok = blockIdx.x;
    int l = tok & (LL - 1);
    int t = threadIdx.x;
    int lane = t & 63, wave = t >> 6;
    int hh = wave * 4 + (lane >> 4);      // head 0..15
    int d0 = (lane & 15) * 4;             // 4 dims = 2 rope pairs
    unsigned short* row = h + (size_t)tok * D1;
    int i0 = d0 >> 1;
    const float* peb = pe + ((size_t)l * 32 + i0) * 4;
    float4 e0 = *(const float4*)(peb);
    float4 e1 = *(const float4*)(peb + 4);
    #pragma unroll
    for (int qk = 0; qk < 2; qk++) {
        unsigned short* p = row + qk * HID + hh * HD + d0;
        const float* sc = (qk == 0 ? q_scale : k_scale) + d0;
        uint2 qv = *(const uint2*)p;
        float v0 = b2f((unsigned short)(qv.x & 0xFFFF)), v1 = b2f((unsigned short)(qv.x >> 16));
        float v2 = b2f((unsigned short)(qv.y & 0xFFFF)), v3 = b2f((unsigned short)(qv.y >> 16));
        float ssq = v0*v0 + v1*v1 + v2*v2 + v3*v3;
        ssq += __shfl_xor(ssq, 1, 16);
        ssq += __shfl_xor(ssq, 2, 16);
        ssq += __shfl_xor(ssq, 4, 16);
        ssq += __shfl_xor(ssq, 8, 16);
        float rr = rsqrtf(ssq * (1.0f / HD) + 1e-6f);
        if (qk == 0) rr *= 0.18033688011112042f;   // 0.125 * log2(e)
        v0 *= rr * sc[0];
        v1 *= rr * sc[1];
        v2 *= rr * sc[2];
        v3 *= rr * sc[3];
        float o0 = e0.x*v0 + e0.y*v1;
        float o1 = e0.z*v0 + e0.w*v1;
        float o2 = e1.x*v2 + e1.y*v3;
        float o3 = e1.z*v2 + e1.w*v3;
        *(uint2*)p = make_uint2(pkbf2(o0, o1), pkbf2(o2, o3));
    }
}

// ---------------- MFMA flash attention (exp2 domain, 64 Q-rows/block) ----------------
#define KT 64            // keys per tile
#define LDP 72           // LDS row pad (bf16 elems)
__global__ __launch_bounds__(256) void k_attn(const unsigned short* __restrict__ h,
                                              unsigned short* __restrict__ cat) {
    __shared__ unsigned short Ks[KT * LDP];        // [key][d]
    __shared__ unsigned short Vt[HD * LDP];        // [d][key]
    __shared__ unsigned short Ps[4 * 16 * LDP];    // per-wave [q][key]
    int t = threadIdx.x;
    int bx = blockIdx.x;               // Q tile 0..31 (64 rows)
    int bh = blockIdx.y;               // 0..31
    int b = bh >> 4, hh = bh & 15;
    int lane = t & 63, w = t >> 6;
    int ln = lane & 15, quad = lane >> 4;
    const unsigned short* hb = h + (size_t)b * LL * D1;

    bf16x8 qf[2];
    {
        const unsigned short* qbase = hb + (size_t)(bx * 64 + w * 16) * D1 + hh * HD;
        #pragma unroll
        for (int ks = 0; ks < 2; ks++)
            qf[ks] = *(const bf16x8*)(qbase + (size_t)ln * D1 + ks * 32 + quad * 8);
    }

    f32x4 O[4];
    #pragma unroll
    for (int vn = 0; vn < 4; vn++) O[vn] = {0.f, 0.f, 0.f, 0.f};
    float m_ = -1e30f, l_ = 0.f;

    unsigned short* Psw = Ps + w * 16 * LDP;

    int skey = t >> 2, sdc = (t & 3) * 16;
    int p2 = (t & 31) * 2, db = (t >> 5) * 8;

    for (int kb = 0; kb < LL / KT; kb++) {
        __syncthreads();
        {   // stage K tile [64][64] -> Ks[key][d]
            const unsigned short* kbase = hb + (size_t)(kb * KT) * D1 + HID + hh * HD;
            u32x4 ka = *(const u32x4*)(kbase + (size_t)skey * D1 + sdc);
            u32x4 kc = *(const u32x4*)(kbase + (size_t)skey * D1 + sdc + 8);
            *(u32x4*)(&Ks[skey * LDP + sdc]) = ka;
            *(u32x4*)(&Ks[skey * LDP + sdc + 8]) = kc;
            // stage V tile transposed -> Vt[d][key]
            const unsigned short* vbase = hb + (size_t)(kb * KT) * D1 + 2 * HID + hh * HD;
            u32x4 va = *(const u32x4*)(vbase + (size_t)p2 * D1 + db);
            u32x4 vb = *(const u32x4*)(vbase + (size_t)(p2 + 1) * D1 + db);
            #pragma unroll
            for (int j = 0; j < 8; j++) {
                unsigned int lo = (j & 1) ? (va[j >> 1] >> 16) : (va[j >> 1] & 0xFFFFu);
                unsigned int hi = (j & 1) ? (vb[j >> 1] >> 16) : (vb[j >> 1] & 0xFFFFu);
                *(unsigned int*)(&Vt[(db + j) * LDP + p2]) = lo | (hi << 16);
            }
        }
        __syncthreads();

        // S^T = K @ Q^T : D[row=key=kt*16+quad*4+r][col=q=ln]
        f32x4 st[4];
        #pragma unroll
        for (int kt = 0; kt < 4; kt++) {
            st[kt] = {0.f, 0.f, 0.f, 0.f};
            #pragma unroll
            for (int ks = 0; ks < 2; ks++) {
                bf16x8 kf = *(const bf16x8*)(&Ks[(kt * 16 + ln) * LDP + ks * 32 + quad * 8]);
                st[kt] = __builtin_amdgcn_mfma_f32_16x16x32_bf16(kf, qf[ks], st[kt], 0, 0, 0);
            }
        }

        // online softmax (exp2 domain)
        {
            float p[16];
            float mx = -1e30f;
            #pragma unroll
            for (int kt = 0; kt < 4; kt++)
                #pragma unroll
                for (int r = 0; r < 4; r++) {
                    float v = st[kt][r];
                    p[kt * 4 + r] = v;
                    mx = fmaxf(mx, v);
                }
            mx = fmaxf(mx, __shfl_xor(mx, 16));
            mx = fmaxf(mx, __shfl_xor(mx, 32));
            float mnew = fmaxf(m_, mx);
            float alpha = __builtin_amdgcn_exp2f(m_ - mnew);
            m_ = mnew;
            float sum = 0.f;
            #pragma unroll
            for (int i = 0; i < 16; i++) {
                float e = __builtin_amdgcn_exp2f(p[i] - mnew);
                p[i] = e;
                sum += e;
            }
            sum += __shfl_xor(sum, 16);
            sum += __shfl_xor(sum, 32);
            l_ = l_ * alpha + sum;
            #pragma unroll
            for (int vn = 0; vn < 4; vn++)
                #pragma unroll
                for (int r = 0; r < 4; r++) O[vn][r] *= alpha;
            #pragma unroll
            for (int kt = 0; kt < 4; kt++) {
                unsigned long long pk =
                    (unsigned long long)pkbf2(p[kt*4+0], p[kt*4+1])
                  | ((unsigned long long)pkbf2(p[kt*4+2], p[kt*4+3]) << 32);
                *(unsigned long long*)(&Psw[ln * LDP + kt * 16 + quad * 4]) = pk;
            }
        }

        // O^T += V^T @ P^T
        #pragma unroll
        for (int kt2 = 0; kt2 < 2; kt2++) {
            bf16x8 pb = *(const bf16x8*)(&Psw[ln * LDP + kt2 * 32 + quad * 8]);
            #pragma unroll
            for (int vn = 0; vn < 4; vn++) {
                bf16x8 vf = *(const bf16x8*)(&Vt[(vn * 16 + ln) * LDP + kt2 * 32 + quad * 8]);
                O[vn] = __builtin_amdgcn_mfma_f32_16x16x32_bf16(vf, pb, O[vn], 0, 0, 0);
            }
        }
    }

    // epilogue: O^T[d][q] / l -> cat[token][hh*64+d]
    {
        float rl = 1.0f / l_;
        size_t row = (size_t)(b * LL + bx * 64 + w * 16 + ln);
        #pragma unroll
        for (int vn = 0; vn < 4; vn++) {
            #pragma unroll
            for (int r2 = 0; r2 < 4; r2 += 2) {
                unsigned int pk = pkbf2(O[vn][r2] * rl, O[vn][r2 + 1] * rl);
                *(unsigned int*)(&cat[row * DCAT + hh * HD + vn * 16 + quad * 4 + r2]) = pk;
            }
        }
    }
}

// ---------------- host launch ----------------
extern "C" void kernel_launch(void* const* d_in, const int* in_sizes, int n_in,
                              void* d_out, int out_size, void* d_ws, size_t ws_size,
                              hipStream_t stream) {
    const float* x       = (const float*)d_in[0];
    const float* vec     = (const float*)d_in[1];
    const float* pe      = (const float*)d_in[2];
    const float* w_mod   = (const float*)d_in[3];
    const float* b_mod   = (const float*)d_in[4];
    const float* w1      = (const float*)d_in[5];
    const float* b1      = (const float*)d_in[6];
    const float* w_mlp   = (const float*)d_in[7];
    const float* b_mlp   = (const float*)d_in[8];
    const float* w2      = (const float*)d_in[9];
    const float* b2      = (const float*)d_in[10];
    const float* q_scale = (const float*)d_in[11];
    const float* k_scale = (const float*)d_in[12];
    float* out = (float*)d_out;

    char* ws = (char*)d_ws;
    size_t off = 0;
    float* mod = (float*)(ws + off);                     off += 6144 * 4;
    unsigned short* xmod  = (unsigned short*)(ws + off); off += (size_t)TOK * HID * 2;
    unsigned short* h     = (unsigned short*)(ws + off); off += (size_t)TOK * D1 * 2;
    unsigned short* cat   = (unsigned short*)(ws + off); off += (size_t)TOK * DCAT * 2;
    unsigned short* w1T   = (unsigned short*)(ws + off); off += (size_t)D1 * HID * 2;
    unsigned short* wmlpT = (unsigned short*)(ws + off); off += (size_t)HID * MLP * 2;
    unsigned short* w2T   = (unsigned short*)(ws + off); off += (size_t)HID * DCAT * 2;
    float* part = (float*)(ws + off);                    off += (size_t)2 * TOK * HID * 4;

    k_transpose_cvt<<<dim3(D1 / 32, HID / 32), dim3(32, 8), 0, stream>>>(w1, w1T, HID, D1);
    k_transpose_cvt<<<dim3(HID / 32, MLP / 32), dim3(32, 8), 0, stream>>>(w_mlp, wmlpT, MLP, HID);
    k_transpose_cvt<<<dim3(HID / 32, DCAT / 32), dim3(32, 8), 0, stream>>>(w2, w2T, DCAT, HID);

    k_mod<<<dim3(96, BB), 256, 0, stream>>>(vec, w_mod, b_mod, mod);
    k_lnmod<<<TOK, 256, 0, stream>>>(x, mod, xmod);

    // h = x_mod @ w1 + b1   (M=4096, N=7168, K=1024)
    k_gemm<0><<<dim3(TOK / 128, D1 / 128), 256, 0, stream>>>(
        xmod, HID, w1T, HID, b1, h, nullptr, D1, HID, nullptr, nullptr);

    k_qkrope<<<TOK, 256, 0, stream>>>(h, pe, q_scale, k_scale);

    k_attn<<<dim3(LL / 64, BB * NH), 256, 0, stream>>>(h, cat);

    // mlp partials: h_mlp @ w_mlp   (M=4096, N=1024, K=4096, split-K=2)
    k_gemm<3><<<dim3(TOK / 128, HID / 128, 2), 256, 0, stream>>>(
        h + DQKV, D1, wmlpT, MLP, b_mlp, nullptr, part, HID, MLP, nullptr, nullptr);
    k_red1<<<TOK * HID / 1024, 256, 0, stream>>>(part, b_mlp, cat);

    // out partials: cat @ w2   (M=4096, N=1024, K=2048, split-K=2)
    k_gemm<3><<<dim3(TOK / 128, HID / 128, 2), 256, 0, stream>>>(
        cat, DCAT, w2T, DCAT, b2, nullptr, part, HID, DCAT, nullptr, nullptr);
    k_red2<<<TOK * HID / 1024, 256, 0, stream>>>(part, b2, x, mod, out);
}